// Round 14
// baseline (155.996 us; speedup 1.0000x reference)
//
#include <hip/hip_runtime.h>
#include <hip/hip_bf16.h>
#include <type_traits>

typedef __attribute__((ext_vector_type(4))) float f32x4;
typedef __attribute__((ext_vector_type(4))) int   i32x4;

static __device__ __forceinline__ void stage16(const void* g, void* l) {
  __builtin_amdgcn_global_load_lds((const __attribute__((address_space(1))) void*)g,
                                   (__attribute__((address_space(3))) void*)l,
                                   16, 0, 0);
}

// ---------------- prep: maxabs(w1/w2) only ----------------
__global__ void prep_kernel(const float4* __restrict__ w1, const float4* __restrict__ w2,
                            int n4w, unsigned* __restrict__ mx) {
  __shared__ unsigned red[4];
  const float4* w = blockIdx.y ? w2 : w1;
  unsigned m = 0;
  const int stride = gridDim.x * blockDim.x;
  for (int i = blockIdx.x * blockDim.x + threadIdx.x; i < n4w; i += stride) {
    float4 v = w[i];
    unsigned a;
    a = __float_as_uint(fabsf(v.x)); m = m > a ? m : a;
    a = __float_as_uint(fabsf(v.y)); m = m > a ? m : a;
    a = __float_as_uint(fabsf(v.z)); m = m > a ? m : a;
    a = __float_as_uint(fabsf(v.w)); m = m > a ? m : a;
  }
#pragma unroll
  for (int off = 32; off > 0; off >>= 1) {
    unsigned t = (unsigned)__shfl_down((int)m, off, 64);
    m = m > t ? m : t;
  }
  if ((threadIdx.x & 63) == 0) red[threadIdx.x >> 6] = m;
  __syncthreads();
  if (threadIdx.x == 0) {
    unsigned t0 = red[0] > red[1] ? red[0] : red[1];
    unsigned t1 = red[2] > red[3] ? red[2] : red[3];
    atomicMax(mx + blockIdx.y, t0 > t1 ? t0 : t1);
  }
}

// y==0: w1 -> int8 (linear) ; y==1: w2 -> int8 pi-permuted within 64-k groups
// (byte p=4*dl+i holds k=dl+16*i) ; y==2: x -> int8 ; y==3 blk0: biases + scale.
__global__ void quantwb_kernel(const float* __restrict__ w1, const float* __restrict__ w2,
                               unsigned char* __restrict__ w1q, unsigned* __restrict__ w2qw,
                               const float4* __restrict__ x, uchar4* __restrict__ xq, int n4x,
                               const float* __restrict__ b1, const float* __restrict__ b2,
                               float* __restrict__ b1i, float* __restrict__ b2i,
                               const unsigned* __restrict__ mx, const float* __restrict__ a_s,
                               float* __restrict__ s_out, int n4, int H, int D) {
  const float ws1 = __uint_as_float(mx[0]) / 127.0f;
  const float ws2 = __uint_as_float(mx[1]) / 127.0f;
  const int stride = gridDim.x * blockDim.x;
  if (blockIdx.y == 0) {
    const float4* w = (const float4*)w1;
    uchar4* wq = (uchar4*)w1q;
    for (int i = blockIdx.x * blockDim.x + threadIdx.x; i < n4; i += stride) {
      float4 v = w[i];
      uchar4 o;
      o.x = (unsigned char)(char)fminf(fmaxf(rintf(v.x / ws1), -127.f), 127.f);
      o.y = (unsigned char)(char)fminf(fmaxf(rintf(v.y / ws1), -127.f), 127.f);
      o.z = (unsigned char)(char)fminf(fmaxf(rintf(v.z / ws1), -127.f), 127.f);
      o.w = (unsigned char)(char)fminf(fmaxf(rintf(v.w / ws1), -127.f), 127.f);
      wq[i] = o;
    }
  } else if (blockIdx.y == 1) {
    const int ndw = n4;                       // D*H/4 dwords
    const int dpr = H >> 2;                   // dwords per row (768)
    for (int g = blockIdx.x * blockDim.x + threadIdx.x; g < ndw; g += stride) {
      const int n = g / dpr;
      const int d = g - n * dpr;
      const int grp = d >> 4, dl = d & 15;
      const float* src = w2 + (size_t)n * H + grp * 64 + dl;
      unsigned r = 0;
#pragma unroll
      for (int i = 0; i < 4; ++i) {
        float v = src[i * 16];
        int q = (int)fminf(fmaxf(rintf(v / ws2), -127.f), 127.f);
        r |= ((unsigned)q & 0xFFu) << (i * 8);
      }
      w2qw[g] = r;
    }
  } else if (blockIdx.y == 2) {
    for (int i = blockIdx.x * blockDim.x + threadIdx.x; i < n4x; i += stride) {
      float4 v = x[i];
      uchar4 o;
      o.x = (unsigned char)(char)fminf(fmaxf(v.x, -127.f), 127.f);
      o.y = (unsigned char)(char)fminf(fmaxf(v.y, -127.f), 127.f);
      o.z = (unsigned char)(char)fminf(fmaxf(v.z, -127.f), 127.f);
      o.w = (unsigned char)(char)fminf(fmaxf(v.w, -127.f), 127.f);
      xq[i] = o;
    }
  } else {
    if (blockIdx.x != 0) return;
    const float s0 = a_s[0];
    const float s1 = s0 * ws1;
    const float d1 = ws1 * s0;
    const float d2 = ws2 * s1;
    if (threadIdx.x == 0) s_out[0] = s1 * ws2;
    for (int i = threadIdx.x; i < H; i += blockDim.x) {
      float q = rintf(b1[i] / d1);
      b1i[i] = fminf(fmaxf(q, -2147483647.f), 2147483647.f);
    }
    for (int i = threadIdx.x; i < D; i += blockDim.x) {
      float q = rintf(b2[i] / d2);
      b2i[i] = fminf(fmaxf(q, -2147483647.f), 2147483647.f);
    }
  }
}

// ---------------- fc1: 256x128 int8, 8 waves (4x2), single-buffer 48KB, 3 blk/CU ----
// vs R13's 128x128: staging bytes/out-elem -25%, blocks halved (1176) so total
// epilogue/prologue cost halves; wave tile stays 64x64 (same ds_read/MFMA ratio).
// Epilogue: per-row-chunk quant, pi-packed dword stores (R12, conflict-free).

__global__ __launch_bounds__(512) void gemm_fc1(
    const char* __restrict__ A, const char* __restrict__ Bt,
    const float* __restrict__ b1f, unsigned char* __restrict__ hq,
    float* __restrict__ stab, int M, int N, int Kb)
{
  __shared__ char lds[49152 + 2048];   // A 32KB | B 16KB | rowtab 2KB
  const int tid = threadIdx.x;
  const int lane = tid & 63;
  const int wave = tid >> 6;
  const int wr = wave >> 1;            // 0..3
  const int wc = wave & 1;             // 0..1

  // 8-row-tile bands, col-major within band (A-band ~1.5MB L2-resident)
  const int nbx = M / 256;             // 49
  const int nby = N / 128;             // 24
  const int bandSize = 8 * nby;
  const int b = blockIdx.x / bandSize;
  const int local = blockIdx.x - b * bandSize;
  const int r0 = b * 8;
  const int rn = min(8, nbx - r0);
  const int c = local / rn;
  const int r = r0 + (local - c * rn);
  const int row0 = r * 256;
  const int col0 = c * 128;

  const int srw = tid >> 3;            // 0..63
  const int chunk = (tid & 7) ^ (srw & 7);
  const char* Ag = A + (size_t)(row0 + srw) * Kb + chunk * 16;
  const char* Bg = Bt + (size_t)(col0 + srw) * Kb + chunk * 16;
  char* const stAp = lds + wave * 1024;            // 512thr x 16B = 8KB/issue
  char* const stBp = lds + 32768 + wave * 1024;

  i32x4 acc[4][4];
#pragma unroll
  for (int i = 0; i < 4; ++i)
#pragma unroll
    for (int j = 0; j < 4; ++j) acc[i][j] = (i32x4)(0);

  const int fr = lane & 15;
  const int fg = lane >> 4;
  const int ocol_l = wc * 64 + fr;
  float bv[4];
#pragma unroll
  for (int nf = 0; nf < 4; ++nf) bv[nf] = b1f[col0 + ocol_l + nf * 16];

  const int xw = (fg ^ (fr & 7)) << 4;
  const int aoff = (wr * 64 + fr) * 128 + xw;
  const int boff = 32768 + (wc * 64 + fr) * 128 + xw;

  const int nS = Kb >> 7;              // 6
  for (int t = 0; t < nS; ++t) {
    const int hb = t << 7;
#pragma unroll
    for (int i = 0; i < 4; ++i)        // A: 256 rows, 64 rows/issue
      stage16(Ag + hb + (size_t)(i * 64) * Kb, stAp + i * 8192);
#pragma unroll
    for (int i = 0; i < 2; ++i)        // B: 128 rows
      stage16(Bg + hb + (size_t)(i * 64) * Kb, stBp + i * 8192);
    __syncthreads();                   // vmcnt(0) drain + barrier
    i32x4 af[2][4], bf[2][4];
#pragma unroll
    for (int h = 0; h < 2; ++h) {
      const int hx = h << 6;
#pragma unroll
      for (int mi = 0; mi < 4; ++mi)
        af[h][mi] = *(const i32x4*)(lds + ((aoff ^ hx) + mi * 2048));
#pragma unroll
      for (int ni = 0; ni < 4; ++ni)
        bf[h][ni] = *(const i32x4*)(lds + ((boff ^ hx) + ni * 2048));
    }
    __builtin_amdgcn_s_setprio(1);
#pragma unroll
    for (int h = 0; h < 2; ++h)
#pragma unroll
      for (int mi = 0; mi < 4; ++mi)
#pragma unroll
        for (int ni = 0; ni < 4; ++ni)
          acc[mi][ni] = __builtin_amdgcn_mfma_i32_16x16x64_i8(
              af[h][mi], bf[h][ni], acc[mi][ni], 0, 0, 0);
    __builtin_amdgcn_s_setprio(0);
    __syncthreads();                   // reads done -> safe overwrite
  }

  // ---- epilogue: per-row-chunk quant, pi-packed coalesced dword stores ----
  float* rowtab = (float*)(lds + 49152);       // [256][2]
  const int orow_l = wr * 64 + fg * 4;         // 0..255

#pragma unroll
  for (int mf = 0; mf < 4; ++mf) {
    float rmax[4] = {0.f, 0.f, 0.f, 0.f};
#pragma unroll
    for (int nf = 0; nf < 4; ++nf)
#pragma unroll
      for (int rg = 0; rg < 4; ++rg) {
        float v = (float)acc[mf][nf][rg] + bv[nf];
        rmax[rg] = fmaxf(rmax[rg], fabsf(v));
      }
#pragma unroll
    for (int rg = 0; rg < 4; ++rg) {
#pragma unroll
      for (int m = 1; m <= 8; m <<= 1)
        rmax[rg] = fmaxf(rmax[rg], __shfl_xor(rmax[rg], m, 64));
      if (fr == 0) rowtab[(orow_l + mf * 16 + rg) * 2 + wc] = rmax[rg];
    }
  }
  __syncthreads();
#pragma unroll
  for (int mf = 0; mf < 4; ++mf) {
#pragma unroll
    for (int rg = 0; rg < 4; ++rg) {
      const int lr = orow_l + mf * 16 + rg;
      float rm = fmaxf(rowtab[lr * 2], rowtab[lr * 2 + 1]);
      float inv = rm > 0.f ? 127.f / rm : 0.f;
      if (wc == 0 && fr == 0) stab[(size_t)(row0 + lr) * 24 + c] = rm * (1.f / 127.f);
      unsigned pk = 0;
#pragma unroll
      for (int nf = 0; nf < 4; ++nf) {
        float v = (float)acc[mf][nf][rg] + bv[nf];
        int q = (int)rintf(v * inv);
        pk |= ((unsigned)q & 0xFFu) << (nf * 8);
      }
      *(unsigned*)(hq + (size_t)(row0 + lr) * N + col0 + wc * 64 + fr * 4) = pk;
    }
  }
}

// ---------------- requant: per-chunk h_q -> per-row h_q' + srow ----------------
__global__ void requant_kernel(const uint4* __restrict__ hq, uint4* __restrict__ hq2,
                               const float* __restrict__ stab, float* __restrict__ srow,
                               int Mrows) {
  const int row = blockIdx.x * 4 + (threadIdx.x >> 6);
  if (row >= Mrows) return;
  const int lane = threadIdx.x & 63;
  const float* st = stab + (size_t)row * 24;
  float sr = 0.f;
#pragma unroll
  for (int i = 0; i < 24; ++i) sr = fmaxf(sr, st[i]);
  if (lane == 0) srow[row] = sr;
  const float rinv = sr > 0.f ? 1.f / sr : 0.f;
  const uint4* in = hq + (size_t)row * 192;
  uint4* outp = hq2 + (size_t)row * 192;
#pragma unroll
  for (int it = 0; it < 3; ++it) {
    const int j = lane + it * 64;
    const float ratio = st[j >> 3] * rinv;
    uint4 iv = in[j], ov;
    unsigned* ip = (unsigned*)&iv;
    unsigned* op = (unsigned*)&ov;
#pragma unroll
    for (int w = 0; w < 4; ++w) {
      unsigned rr = 0;
#pragma unroll
      for (int k = 0; k < 4; ++k) {
        int q = (int)(signed char)((ip[w] >> (k * 8)) & 0xFF);
        int nq = (int)rintf((float)q * ratio);
        rr |= ((unsigned)nq & 0xFF) << (k * 8);
      }
      op[w] = rr;
    }
    outp[j] = ov;
  }
}

// ---------------- fc2: 128x128 pure int8 GEMM (proven loop, unchanged) ----------------
__global__ __launch_bounds__(256) void gemm_fc2(
    const char* __restrict__ A, const char* __restrict__ Bt,
    const float* __restrict__ bias, const float* __restrict__ srow,
    float* __restrict__ Cout, int M, int N, int Kb)
{
  __shared__ char lds[2 * 32768];
  const int tid = threadIdx.x;
  const int lane = tid & 63;
  const int wave = tid >> 6;
  const int wr = wave >> 1;
  const int wc = wave & 1;

  const int nbx = M / 128;
  const int nby = N / 128;
  const int nwg = nbx * nby;
  const int q8 = nwg >> 3, r8 = nwg & 7;
  const int xcd = blockIdx.x & 7, bidx = blockIdx.x >> 3;
  const int wg = (xcd < r8 ? xcd * (q8 + 1) : r8 * (q8 + 1) + (xcd - r8) * q8) + bidx;
  const int r = wg / nby;
  const int c = wg % nby;
  const int row0 = r * 128;
  const int col0 = c * 128;

  const int srw = tid >> 3;
  const int chunk = (tid & 7) ^ (srw & 7);
  const char* Ag = A + (size_t)(row0 + srw) * Kb + chunk * 16;
  const char* Bg = Bt + (size_t)(col0 + srw) * Kb + chunk * 16;
  const int stA = wave * 1024;
  const int stB = 16384 + wave * 1024;

  auto stage = [&](int slot, int h) {
    const int hb = h << 7;
    char* da = lds + slot * 32768 + stA;
    char* db = lds + slot * 32768 + stB;
#pragma unroll
    for (int i = 0; i < 4; ++i)
      stage16(Ag + hb + (size_t)(i * 32) * Kb, da + i * 4096);
#pragma unroll
    for (int i = 0; i < 4; ++i)
      stage16(Bg + hb + (size_t)(i * 32) * Kb, db + i * 4096);
  };

  i32x4 acc[4][4];
#pragma unroll
  for (int i = 0; i < 4; ++i)
#pragma unroll
    for (int j = 0; j < 4; ++j) acc[i][j] = (i32x4)(0);

  const int nS = Kb >> 7;              // 24
  stage(0, 0);
  stage(1, 1);
  asm volatile("s_waitcnt vmcnt(8)" ::: "memory");
  __builtin_amdgcn_s_barrier();

  const int fr = lane & 15;
  const int fg = lane >> 4;
  const int xw = (fg ^ (fr & 7)) << 4;
  const int aoff = (wr * 64 + fr) * 128 + xw;
  const int boff = 16384 + (wc * 64 + fr) * 128 + xw;

  for (int t = 0; t < nS; ++t) {
    const int so = (t & 1) * 32768;
    i32x4 af[2][4], bf[2][4];
#pragma unroll
    for (int h = 0; h < 2; ++h) {
      const int hx = h << 6;
#pragma unroll
      for (int mi = 0; mi < 4; ++mi)
        af[h][mi] = *(const i32x4*)(lds + so + ((aoff ^ hx) + mi * 2048));
#pragma unroll
      for (int ni = 0; ni < 4; ++ni)
        bf[h][ni] = *(const i32x4*)(lds + so + ((boff ^ hx) + ni * 2048));
    }
    asm volatile("s_waitcnt lgkmcnt(0)" ::: "memory");
    __builtin_amdgcn_sched_barrier(0);
    __builtin_amdgcn_s_barrier();
    if (t + 2 < nS) stage(t & 1, t + 2);
    __builtin_amdgcn_s_setprio(1);
#pragma unroll
    for (int h = 0; h < 2; ++h)
#pragma unroll
      for (int mi = 0; mi < 4; ++mi)
#pragma unroll
        for (int ni = 0; ni < 4; ++ni)
          acc[mi][ni] = __builtin_amdgcn_mfma_i32_16x16x64_i8(
              af[h][mi], bf[h][ni], acc[mi][ni], 0, 0, 0);
    __builtin_amdgcn_s_setprio(0);
    if (t + 2 < nS) asm volatile("s_waitcnt vmcnt(8)" ::: "memory");
    else            asm volatile("s_waitcnt vmcnt(0)" ::: "memory");
    __builtin_amdgcn_s_barrier();
  }

  const int orow = row0 + wr * 64 + fg * 4;
  const int ocol = col0 + wc * 64 + fr;
#pragma unroll
  for (int mi = 0; mi < 4; ++mi) {
    float sr[4];
#pragma unroll
    for (int rg = 0; rg < 4; ++rg) sr[rg] = srow[orow + mi * 16 + rg];
#pragma unroll
    for (int ni = 0; ni < 4; ++ni) {
      const int col = ocol + ni * 16;
      const float bv = bias[col];
#pragma unroll
      for (int rg = 0; rg < 4; ++rg) {
        float v = sr[rg] * (float)acc[mi][ni][rg] + bv;
        Cout[(size_t)(orow + mi * 16 + rg) * N + col] = fmaxf(v, 0.f);
      }
    }
  }
}

// ---------------- launch ----------------

extern "C" void kernel_launch(void* const* d_in, const int* in_sizes, int n_in,
                              void* d_out, int out_size, void* d_ws, size_t ws_size,
                              hipStream_t stream) {
  const float* x  = (const float*)d_in[0];
  const float* w1 = (const float*)d_in[1];
  const float* b1 = (const float*)d_in[2];
  const float* w2 = (const float*)d_in[3];
  const float* b2 = (const float*)d_in[4];
  const float* as = (const float*)d_in[5];

  const int Mrows = 64 * 196;   // 12544
  const int D = 768, H = 3072;

  char* ws = (char*)d_ws;
  size_t off = 0;
  auto align256 = [](size_t v) { return (v + 255) & ~(size_t)255; };
  unsigned* mx = (unsigned*)(ws + off); off += 256;
  char* xq8    = (char*)(ws + off);     off += align256((size_t)Mrows * D);
  char* w1q8   = (char*)(ws + off);     off += align256((size_t)H * D);
  char* w2q8   = (char*)(ws + off);     off += align256((size_t)D * H);
  float* b1i = (float*)(ws + off); off += align256((size_t)H * 4);
  float* b2i = (float*)(ws + off); off += align256((size_t)D * 4);
  float* stab = (float*)(ws + off); off += align256((size_t)Mrows * 24 * 4);
  float* srow = (float*)(ws + off); off += align256((size_t)Mrows * 4);
  unsigned char* hq  = (unsigned char*)(ws + off); off += align256((size_t)Mrows * H);
  unsigned char* hq2 = (unsigned char*)(ws + off); off += align256((size_t)Mrows * H);
  if (off > ws_size) return;

  float* out = (float*)d_out;
  float* s_out = out + (out_size - 1);

  hipMemsetAsync(mx, 0, 8, stream);

  const int nw4 = H * D / 4;
  prep_kernel<<<dim3(96, 2), dim3(256), 0, stream>>>(
      (const float4*)w1, (const float4*)w2, nw4, mx);
  quantwb_kernel<<<dim3(1024, 4), dim3(256), 0, stream>>>(
      w1, w2, (unsigned char*)w1q8, (unsigned*)w2q8,
      (const float4*)x, (uchar4*)xq8, Mrows * D / 4,
      b1, b2, b1i, b2i, mx, as, s_out, nw4, H, D);

  // fc1: int8 256x128 single-buffer, 49*24 = 1176 blocks, 3 blocks/CU, Kb = 768
  gemm_fc1<<<dim3((Mrows / 256) * (H / 128)), dim3(512), 0, stream>>>(
      xq8, w1q8, b1i, hq, stab, Mrows, H, D);
  // requant: per-chunk -> per-row scales, 4 rows/block
  requant_kernel<<<dim3(Mrows / 4), dim3(256), 0, stream>>>(
      (const uint4*)hq, (uint4*)hq2, stab, srow, Mrows);
  // fc2: pure int8 128x128, 588 blocks, Kb = 3072
  gemm_fc2<<<dim3((Mrows / 128) * (D / 128)), dim3(256), 0, stream>>>(
      (const char*)hq2, w2q8, b2i, srow, out, Mrows, D, H);
}

// Round 15
// 144.588 us; speedup vs baseline: 1.0789x; 1.0789x over previous
//
#include <hip/hip_runtime.h>
#include <hip/hip_bf16.h>
#include <type_traits>

typedef __attribute__((ext_vector_type(4))) float f32x4;
typedef __attribute__((ext_vector_type(4))) int   i32x4;

static __device__ __forceinline__ void stage16(const void* g, void* l) {
  __builtin_amdgcn_global_load_lds((const __attribute__((address_space(1))) void*)g,
                                   (__attribute__((address_space(3))) void*)l,
                                   16, 0, 0);
}

// ---------------- prep: maxabs(w1/w2) only ----------------
__global__ void prep_kernel(const float4* __restrict__ w1, const float4* __restrict__ w2,
                            int n4w, unsigned* __restrict__ mx) {
  __shared__ unsigned red[4];
  const float4* w = blockIdx.y ? w2 : w1;
  unsigned m = 0;
  const int stride = gridDim.x * blockDim.x;
  for (int i = blockIdx.x * blockDim.x + threadIdx.x; i < n4w; i += stride) {
    float4 v = w[i];
    unsigned a;
    a = __float_as_uint(fabsf(v.x)); m = m > a ? m : a;
    a = __float_as_uint(fabsf(v.y)); m = m > a ? m : a;
    a = __float_as_uint(fabsf(v.z)); m = m > a ? m : a;
    a = __float_as_uint(fabsf(v.w)); m = m > a ? m : a;
  }
#pragma unroll
  for (int off = 32; off > 0; off >>= 1) {
    unsigned t = (unsigned)__shfl_down((int)m, off, 64);
    m = m > t ? m : t;
  }
  if ((threadIdx.x & 63) == 0) red[threadIdx.x >> 6] = m;
  __syncthreads();
  if (threadIdx.x == 0) {
    unsigned t0 = red[0] > red[1] ? red[0] : red[1];
    unsigned t1 = red[2] > red[3] ? red[2] : red[3];
    atomicMax(mx + blockIdx.y, t0 > t1 ? t0 : t1);
  }
}

// y==0: w1 -> int8 (linear) ; y==1: w2 -> int8 pi-permuted within 64-k groups
// (byte p=4*dl+i holds k=dl+16*i) ; y==2: x -> int8 ; y==3 blk0: biases + scale.
__global__ void quantwb_kernel(const float* __restrict__ w1, const float* __restrict__ w2,
                               unsigned char* __restrict__ w1q, unsigned* __restrict__ w2qw,
                               const float4* __restrict__ x, uchar4* __restrict__ xq, int n4x,
                               const float* __restrict__ b1, const float* __restrict__ b2,
                               float* __restrict__ b1i, float* __restrict__ b2i,
                               const unsigned* __restrict__ mx, const float* __restrict__ a_s,
                               float* __restrict__ s_out, int n4, int H, int D) {
  const float ws1 = __uint_as_float(mx[0]) / 127.0f;
  const float ws2 = __uint_as_float(mx[1]) / 127.0f;
  const int stride = gridDim.x * blockDim.x;
  if (blockIdx.y == 0) {
    const float4* w = (const float4*)w1;
    uchar4* wq = (uchar4*)w1q;
    for (int i = blockIdx.x * blockDim.x + threadIdx.x; i < n4; i += stride) {
      float4 v = w[i];
      uchar4 o;
      o.x = (unsigned char)(char)fminf(fmaxf(rintf(v.x / ws1), -127.f), 127.f);
      o.y = (unsigned char)(char)fminf(fmaxf(rintf(v.y / ws1), -127.f), 127.f);
      o.z = (unsigned char)(char)fminf(fmaxf(rintf(v.z / ws1), -127.f), 127.f);
      o.w = (unsigned char)(char)fminf(fmaxf(rintf(v.w / ws1), -127.f), 127.f);
      wq[i] = o;
    }
  } else if (blockIdx.y == 1) {
    const int ndw = n4;                       // D*H/4 dwords
    const int dpr = H >> 2;                   // dwords per row (768)
    for (int g = blockIdx.x * blockDim.x + threadIdx.x; g < ndw; g += stride) {
      const int n = g / dpr;
      const int d = g - n * dpr;
      const int grp = d >> 4, dl = d & 15;
      const float* src = w2 + (size_t)n * H + grp * 64 + dl;
      unsigned r = 0;
#pragma unroll
      for (int i = 0; i < 4; ++i) {
        float v = src[i * 16];
        int q = (int)fminf(fmaxf(rintf(v / ws2), -127.f), 127.f);
        r |= ((unsigned)q & 0xFFu) << (i * 8);
      }
      w2qw[g] = r;
    }
  } else if (blockIdx.y == 2) {
    for (int i = blockIdx.x * blockDim.x + threadIdx.x; i < n4x; i += stride) {
      float4 v = x[i];
      uchar4 o;
      o.x = (unsigned char)(char)fminf(fmaxf(v.x, -127.f), 127.f);
      o.y = (unsigned char)(char)fminf(fmaxf(v.y, -127.f), 127.f);
      o.z = (unsigned char)(char)fminf(fmaxf(v.z, -127.f), 127.f);
      o.w = (unsigned char)(char)fminf(fmaxf(v.w, -127.f), 127.f);
      xq[i] = o;
    }
  } else {
    if (blockIdx.x != 0) return;
    const float s0 = a_s[0];
    const float s1 = s0 * ws1;
    const float d1 = ws1 * s0;
    const float d2 = ws2 * s1;
    if (threadIdx.x == 0) s_out[0] = s1 * ws2;
    for (int i = threadIdx.x; i < H; i += blockDim.x) {
      float q = rintf(b1[i] / d1);
      b1i[i] = fminf(fmaxf(q, -2147483647.f), 2147483647.f);
    }
    for (int i = threadIdx.x; i < D; i += blockDim.x) {
      float q = rintf(b2[i] / d2);
      b2i[i] = fminf(fmaxf(q, -2147483647.f), 2147483647.f);
    }
  }
}

// ---------------- fc1: 128x128 int8, SINGLE-buffer, LDS = exactly 32KB -> 5 blk/CU ----
// R13 structure (proven best: 59.2us at 4 blk/CU). rowtab now OVERLAPS the As slot
// (dead after final K-step barrier) so LDS_Block_Size = 32768 -> 5 blocks/CU.
// Epilogue: per-row-chunk quant, pi-packed dword stores (R12, conflict-free).

__global__ __launch_bounds__(256) void gemm_fc1(
    const char* __restrict__ A, const char* __restrict__ Bt,
    const float* __restrict__ b1f, unsigned char* __restrict__ hq,
    float* __restrict__ stab, int M, int N, int Kb)
{
  __shared__ char lds[32768];          // As 16KB | Bs 16KB ; rowtab reuses As
  const int tid = threadIdx.x;
  const int lane = tid & 63;
  const int wave = tid >> 6;
  const int wr = wave >> 1;
  const int wc = wave & 1;

  // 16-row-tile bands, col-major within band (A-band ~1.5MB L2-resident)
  const int nbx = M / 128;             // 98
  const int nby = N / 128;             // 24
  const int bandSize = 16 * nby;
  const int b = blockIdx.x / bandSize;
  const int local = blockIdx.x - b * bandSize;
  const int r0 = b * 16;
  const int rn = min(16, nbx - r0);
  const int c = local / rn;
  const int r = r0 + (local - c * rn);
  const int row0 = r * 128;
  const int col0 = c * 128;

  const int srw = tid >> 3;
  const int chunk = (tid & 7) ^ (srw & 7);
  const char* Ag = A + (size_t)(row0 + srw) * Kb + chunk * 16;
  const char* Bg = Bt + (size_t)(col0 + srw) * Kb + chunk * 16;
  char* const stAp = lds + wave * 1024;
  char* const stBp = lds + 16384 + wave * 1024;

  i32x4 acc[4][4];
#pragma unroll
  for (int i = 0; i < 4; ++i)
#pragma unroll
    for (int j = 0; j < 4; ++j) acc[i][j] = (i32x4)(0);

  const int fr = lane & 15;
  const int fg = lane >> 4;
  const int ocol_l = wc * 64 + fr;
  float bv[4];
#pragma unroll
  for (int nf = 0; nf < 4; ++nf) bv[nf] = b1f[col0 + ocol_l + nf * 16];

  const int xw = (fg ^ (fr & 7)) << 4;
  const int aoff = (wr * 64 + fr) * 128 + xw;
  const int boff = 16384 + (wc * 64 + fr) * 128 + xw;

  const int nS = Kb >> 7;              // 6
  for (int t = 0; t < nS; ++t) {
    const int hb = t << 7;
#pragma unroll
    for (int i = 0; i < 4; ++i)
      stage16(Ag + hb + (size_t)(i * 32) * Kb, stAp + i * 4096);
#pragma unroll
    for (int i = 0; i < 4; ++i)
      stage16(Bg + hb + (size_t)(i * 32) * Kb, stBp + i * 4096);
    __syncthreads();                   // vmcnt(0) drain + barrier: LDS ready
    i32x4 af[2][4], bf[2][4];
#pragma unroll
    for (int h = 0; h < 2; ++h) {
      const int hx = h << 6;
#pragma unroll
      for (int mi = 0; mi < 4; ++mi)
        af[h][mi] = *(const i32x4*)(lds + ((aoff ^ hx) + mi * 2048));
#pragma unroll
      for (int ni = 0; ni < 4; ++ni)
        bf[h][ni] = *(const i32x4*)(lds + ((boff ^ hx) + ni * 2048));
    }
    __builtin_amdgcn_s_setprio(1);
#pragma unroll
    for (int h = 0; h < 2; ++h)
#pragma unroll
      for (int mi = 0; mi < 4; ++mi)
#pragma unroll
        for (int ni = 0; ni < 4; ++ni)
          acc[mi][ni] = __builtin_amdgcn_mfma_i32_16x16x64_i8(
              af[h][mi], bf[h][ni], acc[mi][ni], 0, 0, 0);
    __builtin_amdgcn_s_setprio(0);
    __syncthreads();                   // all waves' reads done -> safe overwrite
  }

  // ---- epilogue: per-row-chunk quant, pi-packed coalesced dword stores ----
  // rowtab reuses the As region (dead after final barrier above).
  float* rowtab = (float*)lds;                 // [128][2]
  const int orow_l = wr * 64 + fg * 4;

#pragma unroll
  for (int mf = 0; mf < 4; ++mf) {
    float rmax[4] = {0.f, 0.f, 0.f, 0.f};
#pragma unroll
    for (int nf = 0; nf < 4; ++nf)
#pragma unroll
      for (int rg = 0; rg < 4; ++rg) {
        float v = (float)acc[mf][nf][rg] + bv[nf];
        rmax[rg] = fmaxf(rmax[rg], fabsf(v));
      }
#pragma unroll
    for (int rg = 0; rg < 4; ++rg) {
#pragma unroll
      for (int m = 1; m <= 8; m <<= 1)
        rmax[rg] = fmaxf(rmax[rg], __shfl_xor(rmax[rg], m, 64));
      if (fr == 0) rowtab[(orow_l + mf * 16 + rg) * 2 + wc] = rmax[rg];
    }
  }
  __syncthreads();
#pragma unroll
  for (int mf = 0; mf < 4; ++mf) {
#pragma unroll
    for (int rg = 0; rg < 4; ++rg) {
      const int lr = orow_l + mf * 16 + rg;
      float rm = fmaxf(rowtab[lr * 2], rowtab[lr * 2 + 1]);
      float inv = rm > 0.f ? 127.f / rm : 0.f;
      if (wc == 0 && fr == 0) stab[(size_t)(row0 + lr) * 24 + c] = rm * (1.f / 127.f);
      unsigned pk = 0;
#pragma unroll
      for (int nf = 0; nf < 4; ++nf) {
        float v = (float)acc[mf][nf][rg] + bv[nf];
        int q = (int)rintf(v * inv);
        pk |= ((unsigned)q & 0xFFu) << (nf * 8);
      }
      *(unsigned*)(hq + (size_t)(row0 + lr) * N + col0 + wc * 64 + fr * 4) = pk;
    }
  }
}

// ---------------- requant: per-chunk h_q -> per-row h_q' + srow ----------------
__global__ void requant_kernel(const uint4* __restrict__ hq, uint4* __restrict__ hq2,
                               const float* __restrict__ stab, float* __restrict__ srow,
                               int Mrows) {
  const int row = blockIdx.x * 4 + (threadIdx.x >> 6);
  if (row >= Mrows) return;
  const int lane = threadIdx.x & 63;
  const float* st = stab + (size_t)row * 24;
  float sr = 0.f;
#pragma unroll
  for (int i = 0; i < 24; ++i) sr = fmaxf(sr, st[i]);
  if (lane == 0) srow[row] = sr;
  const float rinv = sr > 0.f ? 1.f / sr : 0.f;
  const uint4* in = hq + (size_t)row * 192;
  uint4* outp = hq2 + (size_t)row * 192;
#pragma unroll
  for (int it = 0; it < 3; ++it) {
    const int j = lane + it * 64;
    const float ratio = st[j >> 3] * rinv;
    uint4 iv = in[j], ov;
    unsigned* ip = (unsigned*)&iv;
    unsigned* op = (unsigned*)&ov;
#pragma unroll
    for (int w = 0; w < 4; ++w) {
      unsigned rr = 0;
#pragma unroll
      for (int k = 0; k < 4; ++k) {
        int q = (int)(signed char)((ip[w] >> (k * 8)) & 0xFF);
        int nq = (int)rintf((float)q * ratio);
        rr |= ((unsigned)nq & 0xFF) << (k * 8);
      }
      op[w] = rr;
    }
    outp[j] = ov;
  }
}

// ---------------- fc2: 128x128 pure int8 GEMM (proven loop, unchanged) ----------------
__global__ __launch_bounds__(256) void gemm_fc2(
    const char* __restrict__ A, const char* __restrict__ Bt,
    const float* __restrict__ bias, const float* __restrict__ srow,
    float* __restrict__ Cout, int M, int N, int Kb)
{
  __shared__ char lds[2 * 32768];
  const int tid = threadIdx.x;
  const int lane = tid & 63;
  const int wave = tid >> 6;
  const int wr = wave >> 1;
  const int wc = wave & 1;

  const int nbx = M / 128;
  const int nby = N / 128;
  const int nwg = nbx * nby;
  const int q8 = nwg >> 3, r8 = nwg & 7;
  const int xcd = blockIdx.x & 7, bidx = blockIdx.x >> 3;
  const int wg = (xcd < r8 ? xcd * (q8 + 1) : r8 * (q8 + 1) + (xcd - r8) * q8) + bidx;
  const int r = wg / nby;
  const int c = wg % nby;
  const int row0 = r * 128;
  const int col0 = c * 128;

  const int srw = tid >> 3;
  const int chunk = (tid & 7) ^ (srw & 7);
  const char* Ag = A + (size_t)(row0 + srw) * Kb + chunk * 16;
  const char* Bg = Bt + (size_t)(col0 + srw) * Kb + chunk * 16;
  const int stA = wave * 1024;
  const int stB = 16384 + wave * 1024;

  auto stage = [&](int slot, int h) {
    const int hb = h << 7;
    char* da = lds + slot * 32768 + stA;
    char* db = lds + slot * 32768 + stB;
#pragma unroll
    for (int i = 0; i < 4; ++i)
      stage16(Ag + hb + (size_t)(i * 32) * Kb, da + i * 4096);
#pragma unroll
    for (int i = 0; i < 4; ++i)
      stage16(Bg + hb + (size_t)(i * 32) * Kb, db + i * 4096);
  };

  i32x4 acc[4][4];
#pragma unroll
  for (int i = 0; i < 4; ++i)
#pragma unroll
    for (int j = 0; j < 4; ++j) acc[i][j] = (i32x4)(0);

  const int nS = Kb >> 7;              // 24
  stage(0, 0);
  stage(1, 1);
  asm volatile("s_waitcnt vmcnt(8)" ::: "memory");
  __builtin_amdgcn_s_barrier();

  const int fr = lane & 15;
  const int fg = lane >> 4;
  const int xw = (fg ^ (fr & 7)) << 4;
  const int aoff = (wr * 64 + fr) * 128 + xw;
  const int boff = 16384 + (wc * 64 + fr) * 128 + xw;

  for (int t = 0; t < nS; ++t) {
    const int so = (t & 1) * 32768;
    i32x4 af[2][4], bf[2][4];
#pragma unroll
    for (int h = 0; h < 2; ++h) {
      const int hx = h << 6;
#pragma unroll
      for (int mi = 0; mi < 4; ++mi)
        af[h][mi] = *(const i32x4*)(lds + so + ((aoff ^ hx) + mi * 2048));
#pragma unroll
      for (int ni = 0; ni < 4; ++ni)
        bf[h][ni] = *(const i32x4*)(lds + so + ((boff ^ hx) + ni * 2048));
    }
    asm volatile("s_waitcnt lgkmcnt(0)" ::: "memory");
    __builtin_amdgcn_sched_barrier(0);
    __builtin_amdgcn_s_barrier();
    if (t + 2 < nS) stage(t & 1, t + 2);
    __builtin_amdgcn_s_setprio(1);
#pragma unroll
    for (int h = 0; h < 2; ++h)
#pragma unroll
      for (int mi = 0; mi < 4; ++mi)
#pragma unroll
        for (int ni = 0; ni < 4; ++ni)
          acc[mi][ni] = __builtin_amdgcn_mfma_i32_16x16x64_i8(
              af[h][mi], bf[h][ni], acc[mi][ni], 0, 0, 0);
    __builtin_amdgcn_s_setprio(0);
    if (t + 2 < nS) asm volatile("s_waitcnt vmcnt(8)" ::: "memory");
    else            asm volatile("s_waitcnt vmcnt(0)" ::: "memory");
    __builtin_amdgcn_s_barrier();
  }

  const int orow = row0 + wr * 64 + fg * 4;
  const int ocol = col0 + wc * 64 + fr;
#pragma unroll
  for (int mi = 0; mi < 4; ++mi) {
    float sr[4];
#pragma unroll
    for (int rg = 0; rg < 4; ++rg) sr[rg] = srow[orow + mi * 16 + rg];
#pragma unroll
    for (int ni = 0; ni < 4; ++ni) {
      const int col = ocol + ni * 16;
      const float bv = bias[col];
#pragma unroll
      for (int rg = 0; rg < 4; ++rg) {
        float v = sr[rg] * (float)acc[mi][ni][rg] + bv;
        Cout[(size_t)(orow + mi * 16 + rg) * N + col] = fmaxf(v, 0.f);
      }
    }
  }
}

// ---------------- launch ----------------

extern "C" void kernel_launch(void* const* d_in, const int* in_sizes, int n_in,
                              void* d_out, int out_size, void* d_ws, size_t ws_size,
                              hipStream_t stream) {
  const float* x  = (const float*)d_in[0];
  const float* w1 = (const float*)d_in[1];
  const float* b1 = (const float*)d_in[2];
  const float* w2 = (const float*)d_in[3];
  const float* b2 = (const float*)d_in[4];
  const float* as = (const float*)d_in[5];

  const int Mrows = 64 * 196;   // 12544
  const int D = 768, H = 3072;

  char* ws = (char*)d_ws;
  size_t off = 0;
  auto align256 = [](size_t v) { return (v + 255) & ~(size_t)255; };
  unsigned* mx = (unsigned*)(ws + off); off += 256;
  char* xq8    = (char*)(ws + off);     off += align256((size_t)Mrows * D);
  char* w1q8   = (char*)(ws + off);     off += align256((size_t)H * D);
  char* w2q8   = (char*)(ws + off);     off += align256((size_t)D * H);
  float* b1i = (float*)(ws + off); off += align256((size_t)H * 4);
  float* b2i = (float*)(ws + off); off += align256((size_t)D * 4);
  float* stab = (float*)(ws + off); off += align256((size_t)Mrows * 24 * 4);
  float* srow = (float*)(ws + off); off += align256((size_t)Mrows * 4);
  unsigned char* hq  = (unsigned char*)(ws + off); off += align256((size_t)Mrows * H);
  unsigned char* hq2 = (unsigned char*)(ws + off); off += align256((size_t)Mrows * H);
  if (off > ws_size) return;

  float* out = (float*)d_out;
  float* s_out = out + (out_size - 1);

  hipMemsetAsync(mx, 0, 8, stream);

  const int nw4 = H * D / 4;
  prep_kernel<<<dim3(96, 2), dim3(256), 0, stream>>>(
      (const float4*)w1, (const float4*)w2, nw4, mx);
  quantwb_kernel<<<dim3(1024, 4), dim3(256), 0, stream>>>(
      w1, w2, (unsigned char*)w1q8, (unsigned*)w2q8,
      (const float4*)x, (uchar4*)xq8, Mrows * D / 4,
      b1, b2, b1i, b2i, mx, as, s_out, nw4, H, D);

  // fc1: int8 128x128 single-buffer 32KB, 2352 blocks, 5 blocks/CU, Kb = 768
  gemm_fc1<<<dim3((Mrows / 128) * (H / 128)), dim3(256), 0, stream>>>(
      xq8, w1q8, b1i, hq, stab, Mrows, H, D);
  // requant: per-chunk -> per-row scales, 4 rows/block
  requant_kernel<<<dim3(Mrows / 4), dim3(256), 0, stream>>>(
      (const uint4*)hq, (uint4*)hq2, stab, srow, Mrows);
  // fc2: pure int8 128x128, 588 blocks, Kb = 3072
  gemm_fc2<<<dim3((Mrows / 128) * (D / 128)), dim3(256), 0, stream>>>(
      (const char*)hq2, w2q8, b2i, srow, out, Mrows, D, H);
}

// Round 16
// 137.392 us; speedup vs baseline: 1.1354x; 1.0524x over previous
//
#include <hip/hip_runtime.h>
#include <hip/hip_bf16.h>
#include <type_traits>

typedef __attribute__((ext_vector_type(4))) float f32x4;
typedef __attribute__((ext_vector_type(4))) int   i32x4;

static __device__ __forceinline__ void stage16(const void* g, void* l) {
  __builtin_amdgcn_global_load_lds((const __attribute__((address_space(1))) void*)g,
                                   (__attribute__((address_space(3))) void*)l,
                                   16, 0, 0);
}

// ---------------- prep: maxabs(w1/w2) only ----------------
__global__ void prep_kernel(const float4* __restrict__ w1, const float4* __restrict__ w2,
                            int n4w, unsigned* __restrict__ mx) {
  __shared__ unsigned red[4];
  const float4* w = blockIdx.y ? w2 : w1;
  unsigned m = 0;
  const int stride = gridDim.x * blockDim.x;
  for (int i = blockIdx.x * blockDim.x + threadIdx.x; i < n4w; i += stride) {
    float4 v = w[i];
    unsigned a;
    a = __float_as_uint(fabsf(v.x)); m = m > a ? m : a;
    a = __float_as_uint(fabsf(v.y)); m = m > a ? m : a;
    a = __float_as_uint(fabsf(v.z)); m = m > a ? m : a;
    a = __float_as_uint(fabsf(v.w)); m = m > a ? m : a;
  }
#pragma unroll
  for (int off = 32; off > 0; off >>= 1) {
    unsigned t = (unsigned)__shfl_down((int)m, off, 64);
    m = m > t ? m : t;
  }
  if ((threadIdx.x & 63) == 0) red[threadIdx.x >> 6] = m;
  __syncthreads();
  if (threadIdx.x == 0) {
    unsigned t0 = red[0] > red[1] ? red[0] : red[1];
    unsigned t1 = red[2] > red[3] ? red[2] : red[3];
    atomicMax(mx + blockIdx.y, t0 > t1 ? t0 : t1);
  }
}

// y==0: w1 -> int8 (linear) ; y==1: w2 -> int8 pi-permuted within 64-k groups
// (byte p=4*dl+i holds k=dl+16*i) ; y==2: x -> int8 ; y==3 blk0: biases + scale.
__global__ void quantwb_kernel(const float* __restrict__ w1, const float* __restrict__ w2,
                               unsigned char* __restrict__ w1q, unsigned* __restrict__ w2qw,
                               const float4* __restrict__ x, uchar4* __restrict__ xq, int n4x,
                               const float* __restrict__ b1, const float* __restrict__ b2,
                               float* __restrict__ b1i, float* __restrict__ b2i,
                               const unsigned* __restrict__ mx, const float* __restrict__ a_s,
                               float* __restrict__ s_out, int n4, int H, int D) {
  const float ws1 = __uint_as_float(mx[0]) / 127.0f;
  const float ws2 = __uint_as_float(mx[1]) / 127.0f;
  const int stride = gridDim.x * blockDim.x;
  if (blockIdx.y == 0) {
    const float4* w = (const float4*)w1;
    uchar4* wq = (uchar4*)w1q;
    for (int i = blockIdx.x * blockDim.x + threadIdx.x; i < n4; i += stride) {
      float4 v = w[i];
      uchar4 o;
      o.x = (unsigned char)(char)fminf(fmaxf(rintf(v.x / ws1), -127.f), 127.f);
      o.y = (unsigned char)(char)fminf(fmaxf(rintf(v.y / ws1), -127.f), 127.f);
      o.z = (unsigned char)(char)fminf(fmaxf(rintf(v.z / ws1), -127.f), 127.f);
      o.w = (unsigned char)(char)fminf(fmaxf(rintf(v.w / ws1), -127.f), 127.f);
      wq[i] = o;
    }
  } else if (blockIdx.y == 1) {
    const int ndw = n4;                       // D*H/4 dwords
    const int dpr = H >> 2;                   // dwords per row (768)
    for (int g = blockIdx.x * blockDim.x + threadIdx.x; g < ndw; g += stride) {
      const int n = g / dpr;
      const int d = g - n * dpr;
      const int grp = d >> 4, dl = d & 15;
      const float* src = w2 + (size_t)n * H + grp * 64 + dl;
      unsigned r = 0;
#pragma unroll
      for (int i = 0; i < 4; ++i) {
        float v = src[i * 16];
        int q = (int)fminf(fmaxf(rintf(v / ws2), -127.f), 127.f);
        r |= ((unsigned)q & 0xFFu) << (i * 8);
      }
      w2qw[g] = r;
    }
  } else if (blockIdx.y == 2) {
    for (int i = blockIdx.x * blockDim.x + threadIdx.x; i < n4x; i += stride) {
      float4 v = x[i];
      uchar4 o;
      o.x = (unsigned char)(char)fminf(fmaxf(v.x, -127.f), 127.f);
      o.y = (unsigned char)(char)fminf(fmaxf(v.y, -127.f), 127.f);
      o.z = (unsigned char)(char)fminf(fmaxf(v.z, -127.f), 127.f);
      o.w = (unsigned char)(char)fminf(fmaxf(v.w, -127.f), 127.f);
      xq[i] = o;
    }
  } else {
    if (blockIdx.x != 0) return;
    const float s0 = a_s[0];
    const float s1 = s0 * ws1;
    const float d1 = ws1 * s0;
    const float d2 = ws2 * s1;
    if (threadIdx.x == 0) s_out[0] = s1 * ws2;
    for (int i = threadIdx.x; i < H; i += blockDim.x) {
      float q = rintf(b1[i] / d1);
      b1i[i] = fminf(fmaxf(q, -2147483647.f), 2147483647.f);
    }
    for (int i = threadIdx.x; i < D; i += blockDim.x) {
      float q = rintf(b2[i] / d2);
      b2i[i] = fminf(fmaxf(q, -2147483647.f), 2147483647.f);
    }
  }
}

// ---------------- fc1: 128x128 int8, single-buffer 32KB (R15 loop) ----------------
// Epilogue v2: per-row-chunk quant with chunk = 64 cols = ONE wave tile width.
// Row max needs only a 4-step shfl_xor over the 16 fr lanes -> NO LDS rowtab,
// NO epilogue barriers; v[nf] computed once and held in registers.
// stab[row][48] = chunkmax/127. pi-packed dword stores (conflict-free, coalesced).

__global__ __launch_bounds__(256) void gemm_fc1(
    const char* __restrict__ A, const char* __restrict__ Bt,
    const float* __restrict__ b1f, unsigned char* __restrict__ hq,
    float* __restrict__ stab, int M, int N, int Kb)
{
  __shared__ char lds[32768];          // As 16KB | Bs 16KB
  const int tid = threadIdx.x;
  const int lane = tid & 63;
  const int wave = tid >> 6;
  const int wr = wave >> 1;
  const int wc = wave & 1;

  // 16-row-tile bands, col-major within band (A-band ~1.5MB L2-resident)
  const int nbx = M / 128;             // 98
  const int nby = N / 128;             // 24
  const int bandSize = 16 * nby;
  const int b = blockIdx.x / bandSize;
  const int local = blockIdx.x - b * bandSize;
  const int r0 = b * 16;
  const int rn = min(16, nbx - r0);
  const int c = local / rn;
  const int r = r0 + (local - c * rn);
  const int row0 = r * 128;
  const int col0 = c * 128;

  const int srw = tid >> 3;
  const int chunk = (tid & 7) ^ (srw & 7);
  const char* Ag = A + (size_t)(row0 + srw) * Kb + chunk * 16;
  const char* Bg = Bt + (size_t)(col0 + srw) * Kb + chunk * 16;
  char* const stAp = lds + wave * 1024;
  char* const stBp = lds + 16384 + wave * 1024;

  i32x4 acc[4][4];
#pragma unroll
  for (int i = 0; i < 4; ++i)
#pragma unroll
    for (int j = 0; j < 4; ++j) acc[i][j] = (i32x4)(0);

  const int fr = lane & 15;
  const int fg = lane >> 4;
  const int ocol_l = wc * 64 + fr;
  float bv[4];
#pragma unroll
  for (int nf = 0; nf < 4; ++nf) bv[nf] = b1f[col0 + ocol_l + nf * 16];

  const int xw = (fg ^ (fr & 7)) << 4;
  const int aoff = (wr * 64 + fr) * 128 + xw;
  const int boff = 16384 + (wc * 64 + fr) * 128 + xw;

  const int nS = Kb >> 7;              // 6
  for (int t = 0; t < nS; ++t) {
    const int hb = t << 7;
#pragma unroll
    for (int i = 0; i < 4; ++i)
      stage16(Ag + hb + (size_t)(i * 32) * Kb, stAp + i * 4096);
#pragma unroll
    for (int i = 0; i < 4; ++i)
      stage16(Bg + hb + (size_t)(i * 32) * Kb, stBp + i * 4096);
    __syncthreads();                   // vmcnt(0) drain + barrier: LDS ready
    i32x4 af[2][4], bf[2][4];
#pragma unroll
    for (int h = 0; h < 2; ++h) {
      const int hx = h << 6;
#pragma unroll
      for (int mi = 0; mi < 4; ++mi)
        af[h][mi] = *(const i32x4*)(lds + ((aoff ^ hx) + mi * 2048));
#pragma unroll
      for (int ni = 0; ni < 4; ++ni)
        bf[h][ni] = *(const i32x4*)(lds + ((boff ^ hx) + ni * 2048));
    }
    __builtin_amdgcn_s_setprio(1);
#pragma unroll
    for (int h = 0; h < 2; ++h)
#pragma unroll
      for (int mi = 0; mi < 4; ++mi)
#pragma unroll
        for (int ni = 0; ni < 4; ++ni)
          acc[mi][ni] = __builtin_amdgcn_mfma_i32_16x16x64_i8(
              af[h][mi], bf[h][ni], acc[mi][ni], 0, 0, 0);
    __builtin_amdgcn_s_setprio(0);
    __syncthreads();                   // all waves' reads done -> safe overwrite
  }

  // ---- epilogue: 64-col-chunk quant, barrier-free, pi-packed dword stores ----
  const int orow_l = wr * 64 + fg * 4;
  const int scol = c * 2 + wc;                 // chunk index within stab[row][48]
#pragma unroll
  for (int mf = 0; mf < 4; ++mf) {
#pragma unroll
    for (int rg = 0; rg < 4; ++rg) {
      float v0 = (float)acc[mf][0][rg] + bv[0];
      float v1 = (float)acc[mf][1][rg] + bv[1];
      float v2 = (float)acc[mf][2][rg] + bv[2];
      float v3 = (float)acc[mf][3][rg] + bv[3];
      float rmax = fmaxf(fmaxf(fabsf(v0), fabsf(v1)), fmaxf(fabsf(v2), fabsf(v3)));
#pragma unroll
      for (int m = 1; m <= 8; m <<= 1)
        rmax = fmaxf(rmax, __shfl_xor(rmax, m, 64));   // reduce over fr lanes
      const int lr = orow_l + mf * 16 + rg;
      const float inv = rmax > 0.f ? 127.f / rmax : 0.f;
      if (fr == 0) stab[(size_t)(row0 + lr) * 48 + scol] = rmax * (1.f / 127.f);
      unsigned pk = ((unsigned)(int)rintf(v0 * inv) & 0xFFu)
                  | (((unsigned)(int)rintf(v1 * inv) & 0xFFu) << 8)
                  | (((unsigned)(int)rintf(v2 * inv) & 0xFFu) << 16)
                  | (((unsigned)(int)rintf(v3 * inv) & 0xFFu) << 24);
      *(unsigned*)(hq + (size_t)(row0 + lr) * N + col0 + wc * 64 + fr * 4) = pk;
    }
  }
}

// ---------------- requant: per-64col-chunk h_q -> per-row h_q' + srow ----------------
// 4 rows/block. Byte positions are pi-permuted within 64-col groups, which align
// exactly with the 64-col scale chunks -> ratio per 16B vector = st[j>>2].
__global__ void requant_kernel(const uint4* __restrict__ hq, uint4* __restrict__ hq2,
                               const float* __restrict__ stab, float* __restrict__ srow,
                               int Mrows) {
  const int row = blockIdx.x * 4 + (threadIdx.x >> 6);
  if (row >= Mrows) return;
  const int lane = threadIdx.x & 63;
  const float* st = stab + (size_t)row * 48;
  float sr = 0.f;
#pragma unroll
  for (int i = 0; i < 12; ++i) {
    float4 s4 = ((const float4*)st)[i];
    sr = fmaxf(sr, fmaxf(fmaxf(s4.x, s4.y), fmaxf(s4.z, s4.w)));
  }
  if (lane == 0) srow[row] = sr;
  const float rinv = sr > 0.f ? 1.f / sr : 0.f;
  const uint4* in = hq + (size_t)row * 192;
  uint4* outp = hq2 + (size_t)row * 192;
#pragma unroll
  for (int it = 0; it < 3; ++it) {
    const int j = lane + it * 64;
    const float ratio = st[j >> 2] * rinv;
    uint4 iv = in[j], ov;
    unsigned* ip = (unsigned*)&iv;
    unsigned* op = (unsigned*)&ov;
#pragma unroll
    for (int w = 0; w < 4; ++w) {
      unsigned rr = 0;
#pragma unroll
      for (int k = 0; k < 4; ++k) {
        int q = (int)(signed char)((ip[w] >> (k * 8)) & 0xFF);
        int nq = (int)rintf((float)q * ratio);
        rr |= ((unsigned)nq & 0xFF) << (k * 8);
      }
      op[w] = rr;
    }
    outp[j] = ov;
  }
}

// ---------------- fc2: 128x128 pure int8 GEMM (proven loop, unchanged) ----------------
__global__ __launch_bounds__(256) void gemm_fc2(
    const char* __restrict__ A, const char* __restrict__ Bt,
    const float* __restrict__ bias, const float* __restrict__ srow,
    float* __restrict__ Cout, int M, int N, int Kb)
{
  __shared__ char lds[2 * 32768];
  const int tid = threadIdx.x;
  const int lane = tid & 63;
  const int wave = tid >> 6;
  const int wr = wave >> 1;
  const int wc = wave & 1;

  const int nbx = M / 128;
  const int nby = N / 128;
  const int nwg = nbx * nby;
  const int q8 = nwg >> 3, r8 = nwg & 7;
  const int xcd = blockIdx.x & 7, bidx = blockIdx.x >> 3;
  const int wg = (xcd < r8 ? xcd * (q8 + 1) : r8 * (q8 + 1) + (xcd - r8) * q8) + bidx;
  const int r = wg / nby;
  const int c = wg % nby;
  const int row0 = r * 128;
  const int col0 = c * 128;

  const int srw = tid >> 3;
  const int chunk = (tid & 7) ^ (srw & 7);
  const char* Ag = A + (size_t)(row0 + srw) * Kb + chunk * 16;
  const char* Bg = Bt + (size_t)(col0 + srw) * Kb + chunk * 16;
  const int stA = wave * 1024;
  const int stB = 16384 + wave * 1024;

  auto stage = [&](int slot, int h) {
    const int hb = h << 7;
    char* da = lds + slot * 32768 + stA;
    char* db = lds + slot * 32768 + stB;
#pragma unroll
    for (int i = 0; i < 4; ++i)
      stage16(Ag + hb + (size_t)(i * 32) * Kb, da + i * 4096);
#pragma unroll
    for (int i = 0; i < 4; ++i)
      stage16(Bg + hb + (size_t)(i * 32) * Kb, db + i * 4096);
  };

  i32x4 acc[4][4];
#pragma unroll
  for (int i = 0; i < 4; ++i)
#pragma unroll
    for (int j = 0; j < 4; ++j) acc[i][j] = (i32x4)(0);

  const int nS = Kb >> 7;              // 24
  stage(0, 0);
  stage(1, 1);
  asm volatile("s_waitcnt vmcnt(8)" ::: "memory");
  __builtin_amdgcn_s_barrier();

  const int fr = lane & 15;
  const int fg = lane >> 4;
  const int xw = (fg ^ (fr & 7)) << 4;
  const int aoff = (wr * 64 + fr) * 128 + xw;
  const int boff = 16384 + (wc * 64 + fr) * 128 + xw;

  for (int t = 0; t < nS; ++t) {
    const int so = (t & 1) * 32768;
    i32x4 af[2][4], bf[2][4];
#pragma unroll
    for (int h = 0; h < 2; ++h) {
      const int hx = h << 6;
#pragma unroll
      for (int mi = 0; mi < 4; ++mi)
        af[h][mi] = *(const i32x4*)(lds + so + ((aoff ^ hx) + mi * 2048));
#pragma unroll
      for (int ni = 0; ni < 4; ++ni)
        bf[h][ni] = *(const i32x4*)(lds + so + ((boff ^ hx) + ni * 2048));
    }
    asm volatile("s_waitcnt lgkmcnt(0)" ::: "memory");
    __builtin_amdgcn_sched_barrier(0);
    __builtin_amdgcn_s_barrier();
    if (t + 2 < nS) stage(t & 1, t + 2);
    __builtin_amdgcn_s_setprio(1);
#pragma unroll
    for (int h = 0; h < 2; ++h)
#pragma unroll
      for (int mi = 0; mi < 4; ++mi)
#pragma unroll
        for (int ni = 0; ni < 4; ++ni)
          acc[mi][ni] = __builtin_amdgcn_mfma_i32_16x16x64_i8(
              af[h][mi], bf[h][ni], acc[mi][ni], 0, 0, 0);
    __builtin_amdgcn_s_setprio(0);
    if (t + 2 < nS) asm volatile("s_waitcnt vmcnt(8)" ::: "memory");
    else            asm volatile("s_waitcnt vmcnt(0)" ::: "memory");
    __builtin_amdgcn_s_barrier();
  }

  const int orow = row0 + wr * 64 + fg * 4;
  const int ocol = col0 + wc * 64 + fr;
#pragma unroll
  for (int mi = 0; mi < 4; ++mi) {
    float sr[4];
#pragma unroll
    for (int rg = 0; rg < 4; ++rg) sr[rg] = srow[orow + mi * 16 + rg];
#pragma unroll
    for (int ni = 0; ni < 4; ++ni) {
      const int col = ocol + ni * 16;
      const float bv = bias[col];
#pragma unroll
      for (int rg = 0; rg < 4; ++rg) {
        float v = sr[rg] * (float)acc[mi][ni][rg] + bv;
        Cout[(size_t)(orow + mi * 16 + rg) * N + col] = fmaxf(v, 0.f);
      }
    }
  }
}

// ---------------- launch ----------------

extern "C" void kernel_launch(void* const* d_in, const int* in_sizes, int n_in,
                              void* d_out, int out_size, void* d_ws, size_t ws_size,
                              hipStream_t stream) {
  const float* x  = (const float*)d_in[0];
  const float* w1 = (const float*)d_in[1];
  const float* b1 = (const float*)d_in[2];
  const float* w2 = (const float*)d_in[3];
  const float* b2 = (const float*)d_in[4];
  const float* as = (const float*)d_in[5];

  const int Mrows = 64 * 196;   // 12544
  const int D = 768, H = 3072;

  char* ws = (char*)d_ws;
  size_t off = 0;
  auto align256 = [](size_t v) { return (v + 255) & ~(size_t)255; };
  unsigned* mx = (unsigned*)(ws + off); off += 256;
  char* xq8    = (char*)(ws + off);     off += align256((size_t)Mrows * D);
  char* w1q8   = (char*)(ws + off);     off += align256((size_t)H * D);
  char* w2q8   = (char*)(ws + off);     off += align256((size_t)D * H);
  float* b1i = (float*)(ws + off); off += align256((size_t)H * 4);
  float* b2i = (float*)(ws + off); off += align256((size_t)D * 4);
  float* stab = (float*)(ws + off); off += align256((size_t)Mrows * 48 * 4);
  float* srow = (float*)(ws + off); off += align256((size_t)Mrows * 4);
  unsigned char* hq  = (unsigned char*)(ws + off); off += align256((size_t)Mrows * H);
  unsigned char* hq2 = (unsigned char*)(ws + off); off += align256((size_t)Mrows * H);
  if (off > ws_size) return;

  float* out = (float*)d_out;
  float* s_out = out + (out_size - 1);

  hipMemsetAsync(mx, 0, 8, stream);

  const int nw4 = H * D / 4;
  prep_kernel<<<dim3(96, 2), dim3(256), 0, stream>>>(
      (const float4*)w1, (const float4*)w2, nw4, mx);
  quantwb_kernel<<<dim3(1024, 4), dim3(256), 0, stream>>>(
      w1, w2, (unsigned char*)w1q8, (unsigned*)w2q8,
      (const float4*)x, (uchar4*)xq8, Mrows * D / 4,
      b1, b2, b1i, b2i, mx, as, s_out, nw4, H, D);

  // fc1: int8 128x128 single-buffer 32KB, 2352 blocks, Kb = 768
  gemm_fc1<<<dim3((Mrows / 128) * (H / 128)), dim3(256), 0, stream>>>(
      xq8, w1q8, b1i, hq, stab, Mrows, H, D);
  // requant: per-64col-chunk -> per-row scales, 4 rows/block
  requant_kernel<<<dim3(Mrows / 4), dim3(256), 0, stream>>>(
      (const uint4*)hq, (uint4*)hq2, stab, srow, Mrows);
  // fc2: pure int8 128x128, 588 blocks, Kb = 3072
  gemm_fc2<<<dim3((Mrows / 128) * (D / 128)), dim3(256), 0, stream>>>(
      (const char*)hq2, w2q8, b2i, srow, out, Mrows, D, H);
}

// Round 17
// 133.751 us; speedup vs baseline: 1.1663x; 1.0272x over previous
//
#include <hip/hip_runtime.h>
#include <hip/hip_bf16.h>
#include <type_traits>

typedef __attribute__((ext_vector_type(4))) float f32x4;
typedef __attribute__((ext_vector_type(4))) int   i32x4;

static __device__ __forceinline__ void stage16(const void* g, void* l) {
  __builtin_amdgcn_global_load_lds((const __attribute__((address_space(1))) void*)g,
                                   (__attribute__((address_space(3))) void*)l,
                                   16, 0, 0);
}

// ---------------- prep: maxabs(w1/w2) only ----------------
__global__ void prep_kernel(const float4* __restrict__ w1, const float4* __restrict__ w2,
                            int n4w, unsigned* __restrict__ mx) {
  __shared__ unsigned red[4];
  const float4* w = blockIdx.y ? w2 : w1;
  unsigned m = 0;
  const int stride = gridDim.x * blockDim.x;
  for (int i = blockIdx.x * blockDim.x + threadIdx.x; i < n4w; i += stride) {
    float4 v = w[i];
    unsigned a;
    a = __float_as_uint(fabsf(v.x)); m = m > a ? m : a;
    a = __float_as_uint(fabsf(v.y)); m = m > a ? m : a;
    a = __float_as_uint(fabsf(v.z)); m = m > a ? m : a;
    a = __float_as_uint(fabsf(v.w)); m = m > a ? m : a;
  }
#pragma unroll
  for (int off = 32; off > 0; off >>= 1) {
    unsigned t = (unsigned)__shfl_down((int)m, off, 64);
    m = m > t ? m : t;
  }
  if ((threadIdx.x & 63) == 0) red[threadIdx.x >> 6] = m;
  __syncthreads();
  if (threadIdx.x == 0) {
    unsigned t0 = red[0] > red[1] ? red[0] : red[1];
    unsigned t1 = red[2] > red[3] ? red[2] : red[3];
    atomicMax(mx + blockIdx.y, t0 > t1 ? t0 : t1);
  }
}

// y==0: w1 -> int8 (linear) ; y==1: w2 -> int8 pi-permuted within 64-k groups
// (byte p=4*dl+i holds k=dl+16*i) ; y==2: x -> int8 ; y==3 blk0: biases + scale.
__global__ void quantwb_kernel(const float* __restrict__ w1, const float* __restrict__ w2,
                               unsigned char* __restrict__ w1q, unsigned* __restrict__ w2qw,
                               const float4* __restrict__ x, uchar4* __restrict__ xq, int n4x,
                               const float* __restrict__ b1, const float* __restrict__ b2,
                               float* __restrict__ b1i, float* __restrict__ b2i,
                               const unsigned* __restrict__ mx, const float* __restrict__ a_s,
                               float* __restrict__ s_out, int n4, int H, int D) {
  const float ws1 = __uint_as_float(mx[0]) / 127.0f;
  const float ws2 = __uint_as_float(mx[1]) / 127.0f;
  const int stride = gridDim.x * blockDim.x;
  if (blockIdx.y == 0) {
    const float4* w = (const float4*)w1;
    uchar4* wq = (uchar4*)w1q;
    for (int i = blockIdx.x * blockDim.x + threadIdx.x; i < n4; i += stride) {
      float4 v = w[i];
      uchar4 o;
      o.x = (unsigned char)(char)fminf(fmaxf(rintf(v.x / ws1), -127.f), 127.f);
      o.y = (unsigned char)(char)fminf(fmaxf(rintf(v.y / ws1), -127.f), 127.f);
      o.z = (unsigned char)(char)fminf(fmaxf(rintf(v.z / ws1), -127.f), 127.f);
      o.w = (unsigned char)(char)fminf(fmaxf(rintf(v.w / ws1), -127.f), 127.f);
      wq[i] = o;
    }
  } else if (blockIdx.y == 1) {
    const int ndw = n4;                       // D*H/4 dwords
    const int dpr = H >> 2;                   // dwords per row (768)
    for (int g = blockIdx.x * blockDim.x + threadIdx.x; g < ndw; g += stride) {
      const int n = g / dpr;
      const int d = g - n * dpr;
      const int grp = d >> 4, dl = d & 15;
      const float* src = w2 + (size_t)n * H + grp * 64 + dl;
      unsigned r = 0;
#pragma unroll
      for (int i = 0; i < 4; ++i) {
        float v = src[i * 16];
        int q = (int)fminf(fmaxf(rintf(v / ws2), -127.f), 127.f);
        r |= ((unsigned)q & 0xFFu) << (i * 8);
      }
      w2qw[g] = r;
    }
  } else if (blockIdx.y == 2) {
    for (int i = blockIdx.x * blockDim.x + threadIdx.x; i < n4x; i += stride) {
      float4 v = x[i];
      uchar4 o;
      o.x = (unsigned char)(char)fminf(fmaxf(v.x, -127.f), 127.f);
      o.y = (unsigned char)(char)fminf(fmaxf(v.y, -127.f), 127.f);
      o.z = (unsigned char)(char)fminf(fmaxf(v.z, -127.f), 127.f);
      o.w = (unsigned char)(char)fminf(fmaxf(v.w, -127.f), 127.f);
      xq[i] = o;
    }
  } else {
    if (blockIdx.x != 0) return;
    const float s0 = a_s[0];
    const float s1 = s0 * ws1;
    const float d1 = ws1 * s0;
    const float d2 = ws2 * s1;
    if (threadIdx.x == 0) s_out[0] = s1 * ws2;
    for (int i = threadIdx.x; i < H; i += blockDim.x) {
      float q = rintf(b1[i] / d1);
      b1i[i] = fminf(fmaxf(q, -2147483647.f), 2147483647.f);
    }
    for (int i = threadIdx.x; i < D; i += blockDim.x) {
      float q = rintf(b2[i] / d2);
      b2i[i] = fminf(fmaxf(q, -2147483647.f), 2147483647.f);
    }
  }
}

// ---------------- fc1: 128x128 int8, single-buffer 32KB (R16, frozen) ----------------
__global__ __launch_bounds__(256) void gemm_fc1(
    const char* __restrict__ A, const char* __restrict__ Bt,
    const float* __restrict__ b1f, unsigned char* __restrict__ hq,
    float* __restrict__ stab, int M, int N, int Kb)
{
  __shared__ char lds[32768];          // As 16KB | Bs 16KB
  const int tid = threadIdx.x;
  const int lane = tid & 63;
  const int wave = tid >> 6;
  const int wr = wave >> 1;
  const int wc = wave & 1;

  // 16-row-tile bands, col-major within band (A-band ~1.5MB L2-resident)
  const int nbx = M / 128;             // 98
  const int nby = N / 128;             // 24
  const int bandSize = 16 * nby;
  const int b = blockIdx.x / bandSize;
  const int local = blockIdx.x - b * bandSize;
  const int r0 = b * 16;
  const int rn = min(16, nbx - r0);
  const int c = local / rn;
  const int r = r0 + (local - c * rn);
  const int row0 = r * 128;
  const int col0 = c * 128;

  const int srw = tid >> 3;
  const int chunk = (tid & 7) ^ (srw & 7);
  const char* Ag = A + (size_t)(row0 + srw) * Kb + chunk * 16;
  const char* Bg = Bt + (size_t)(col0 + srw) * Kb + chunk * 16;
  char* const stAp = lds + wave * 1024;
  char* const stBp = lds + 16384 + wave * 1024;

  i32x4 acc[4][4];
#pragma unroll
  for (int i = 0; i < 4; ++i)
#pragma unroll
    for (int j = 0; j < 4; ++j) acc[i][j] = (i32x4)(0);

  const int fr = lane & 15;
  const int fg = lane >> 4;
  const int ocol_l = wc * 64 + fr;
  float bv[4];
#pragma unroll
  for (int nf = 0; nf < 4; ++nf) bv[nf] = b1f[col0 + ocol_l + nf * 16];

  const int xw = (fg ^ (fr & 7)) << 4;
  const int aoff = (wr * 64 + fr) * 128 + xw;
  const int boff = 16384 + (wc * 64 + fr) * 128 + xw;

  const int nS = Kb >> 7;              // 6
  for (int t = 0; t < nS; ++t) {
    const int hb = t << 7;
#pragma unroll
    for (int i = 0; i < 4; ++i)
      stage16(Ag + hb + (size_t)(i * 32) * Kb, stAp + i * 4096);
#pragma unroll
    for (int i = 0; i < 4; ++i)
      stage16(Bg + hb + (size_t)(i * 32) * Kb, stBp + i * 4096);
    __syncthreads();                   // vmcnt(0) drain + barrier: LDS ready
    i32x4 af[2][4], bf[2][4];
#pragma unroll
    for (int h = 0; h < 2; ++h) {
      const int hx = h << 6;
#pragma unroll
      for (int mi = 0; mi < 4; ++mi)
        af[h][mi] = *(const i32x4*)(lds + ((aoff ^ hx) + mi * 2048));
#pragma unroll
      for (int ni = 0; ni < 4; ++ni)
        bf[h][ni] = *(const i32x4*)(lds + ((boff ^ hx) + ni * 2048));
    }
    __builtin_amdgcn_s_setprio(1);
#pragma unroll
    for (int h = 0; h < 2; ++h)
#pragma unroll
      for (int mi = 0; mi < 4; ++mi)
#pragma unroll
        for (int ni = 0; ni < 4; ++ni)
          acc[mi][ni] = __builtin_amdgcn_mfma_i32_16x16x64_i8(
              af[h][mi], bf[h][ni], acc[mi][ni], 0, 0, 0);
    __builtin_amdgcn_s_setprio(0);
    __syncthreads();                   // all waves' reads done -> safe overwrite
  }

  // ---- epilogue: 64-col-chunk quant, barrier-free, pi-packed dword stores ----
  const int orow_l = wr * 64 + fg * 4;
  const int scol = c * 2 + wc;                 // chunk index within stab[row][48]
#pragma unroll
  for (int mf = 0; mf < 4; ++mf) {
#pragma unroll
    for (int rg = 0; rg < 4; ++rg) {
      float v0 = (float)acc[mf][0][rg] + bv[0];
      float v1 = (float)acc[mf][1][rg] + bv[1];
      float v2 = (float)acc[mf][2][rg] + bv[2];
      float v3 = (float)acc[mf][3][rg] + bv[3];
      float rmax = fmaxf(fmaxf(fabsf(v0), fabsf(v1)), fmaxf(fabsf(v2), fabsf(v3)));
#pragma unroll
      for (int m = 1; m <= 8; m <<= 1)
        rmax = fmaxf(rmax, __shfl_xor(rmax, m, 64));   // reduce over fr lanes
      const int lr = orow_l + mf * 16 + rg;
      const float inv = rmax > 0.f ? 127.f / rmax : 0.f;
      if (fr == 0) stab[(size_t)(row0 + lr) * 48 + scol] = rmax * (1.f / 127.f);
      unsigned pk = ((unsigned)(int)rintf(v0 * inv) & 0xFFu)
                  | (((unsigned)(int)rintf(v1 * inv) & 0xFFu) << 8)
                  | (((unsigned)(int)rintf(v2 * inv) & 0xFFu) << 16)
                  | (((unsigned)(int)rintf(v3 * inv) & 0xFFu) << 24);
      *(unsigned*)(hq + (size_t)(row0 + lr) * N + col0 + wc * 64 + fr * 4) = pk;
    }
  }
}

// ---------------- requant: per-64col-chunk h_q -> per-row h_q' + srow ----------------
__global__ void requant_kernel(const uint4* __restrict__ hq, uint4* __restrict__ hq2,
                               const float* __restrict__ stab, float* __restrict__ srow,
                               int Mrows) {
  const int row = blockIdx.x * 4 + (threadIdx.x >> 6);
  if (row >= Mrows) return;
  const int lane = threadIdx.x & 63;
  const float* st = stab + (size_t)row * 48;
  float sr = 0.f;
#pragma unroll
  for (int i = 0; i < 12; ++i) {
    float4 s4 = ((const float4*)st)[i];
    sr = fmaxf(sr, fmaxf(fmaxf(s4.x, s4.y), fmaxf(s4.z, s4.w)));
  }
  if (lane == 0) srow[row] = sr;
  const float rinv = sr > 0.f ? 1.f / sr : 0.f;
  const uint4* in = hq + (size_t)row * 192;
  uint4* outp = hq2 + (size_t)row * 192;
#pragma unroll
  for (int it = 0; it < 3; ++it) {
    const int j = lane + it * 64;
    const float ratio = st[j >> 2] * rinv;
    uint4 iv = in[j], ov;
    unsigned* ip = (unsigned*)&iv;
    unsigned* op = (unsigned*)&ov;
#pragma unroll
    for (int w = 0; w < 4; ++w) {
      unsigned rr = 0;
#pragma unroll
      for (int k = 0; k < 4; ++k) {
        int q = (int)(signed char)((ip[w] >> (k * 8)) & 0xFF);
        int nq = (int)rintf((float)q * ratio);
        rr |= ((unsigned)nq & 0xFF) << (k * 8);
      }
      op[w] = rr;
    }
    outp[j] = ov;
  }
}

// ---------------- fc2: 128x128 int8, SINGLE-buffer 32KB -> 5 blocks/CU ----------------
// Clean A/B vs the 2-slot dbuf (64KB, 2 blk/CU): fc1's R13-vs-R11 result says the
// per-step drain hides better under 5 independent resident blocks than a 2-deep
// pipeline at 2 blk/CU. All 588 blocks co-resident (zero tail). Row-major + m204 kept.

__global__ __launch_bounds__(256) void gemm_fc2(
    const char* __restrict__ A, const char* __restrict__ Bt,
    const float* __restrict__ bias, const float* __restrict__ srow,
    float* __restrict__ Cout, int M, int N, int Kb)
{
  __shared__ char lds[32768];          // As 16KB | Bs 16KB
  const int tid = threadIdx.x;
  const int lane = tid & 63;
  const int wave = tid >> 6;
  const int wr = wave >> 1;
  const int wc = wave & 1;

  const int nbx = M / 128;
  const int nby = N / 128;
  const int nwg = nbx * nby;
  const int q8 = nwg >> 3, r8 = nwg & 7;
  const int xcd = blockIdx.x & 7, bidx = blockIdx.x >> 3;
  const int wg = (xcd < r8 ? xcd * (q8 + 1) : r8 * (q8 + 1) + (xcd - r8) * q8) + bidx;
  const int r = wg / nby;              // row-major: same-row tiles adjacent -> same XCD
  const int c = wg % nby;
  const int row0 = r * 128;
  const int col0 = c * 128;

  const int srw = tid >> 3;
  const int chunk = (tid & 7) ^ (srw & 7);
  const char* Ag = A + (size_t)(row0 + srw) * Kb + chunk * 16;
  const char* Bg = Bt + (size_t)(col0 + srw) * Kb + chunk * 16;
  char* const stAp = lds + wave * 1024;
  char* const stBp = lds + 16384 + wave * 1024;

  i32x4 acc[4][4];
#pragma unroll
  for (int i = 0; i < 4; ++i)
#pragma unroll
    for (int j = 0; j < 4; ++j) acc[i][j] = (i32x4)(0);

  const int fr = lane & 15;
  const int fg = lane >> 4;
  const int xw = (fg ^ (fr & 7)) << 4;
  const int aoff = (wr * 64 + fr) * 128 + xw;
  const int boff = 16384 + (wc * 64 + fr) * 128 + xw;

  const int nS = Kb >> 7;              // 24
  for (int t = 0; t < nS; ++t) {
    const int hb = t << 7;
#pragma unroll
    for (int i = 0; i < 4; ++i)
      stage16(Ag + hb + (size_t)(i * 32) * Kb, stAp + i * 4096);
#pragma unroll
    for (int i = 0; i < 4; ++i)
      stage16(Bg + hb + (size_t)(i * 32) * Kb, stBp + i * 4096);
    __syncthreads();                   // vmcnt(0) drain + barrier: LDS ready
    i32x4 af[2][4], bf[2][4];
#pragma unroll
    for (int h = 0; h < 2; ++h) {
      const int hx = h << 6;
#pragma unroll
      for (int mi = 0; mi < 4; ++mi)
        af[h][mi] = *(const i32x4*)(lds + ((aoff ^ hx) + mi * 2048));
#pragma unroll
      for (int ni = 0; ni < 4; ++ni)
        bf[h][ni] = *(const i32x4*)(lds + ((boff ^ hx) + ni * 2048));
    }
    __builtin_amdgcn_s_setprio(1);
#pragma unroll
    for (int h = 0; h < 2; ++h)
#pragma unroll
      for (int mi = 0; mi < 4; ++mi)
#pragma unroll
        for (int ni = 0; ni < 4; ++ni)
          acc[mi][ni] = __builtin_amdgcn_mfma_i32_16x16x64_i8(
              af[h][mi], bf[h][ni], acc[mi][ni], 0, 0, 0);
    __builtin_amdgcn_s_setprio(0);
    __syncthreads();                   // all waves' reads done -> safe overwrite
  }

  const int orow = row0 + wr * 64 + fg * 4;
  const int ocol = col0 + wc * 64 + fr;
#pragma unroll
  for (int mi = 0; mi < 4; ++mi) {
    float sr[4];
#pragma unroll
    for (int rg = 0; rg < 4; ++rg) sr[rg] = srow[orow + mi * 16 + rg];
#pragma unroll
    for (int ni = 0; ni < 4; ++ni) {
      const int col = ocol + ni * 16;
      const float bv = bias[col];
#pragma unroll
      for (int rg = 0; rg < 4; ++rg) {
        float v = sr[rg] * (float)acc[mi][ni][rg] + bv;
        Cout[(size_t)(orow + mi * 16 + rg) * N + col] = fmaxf(v, 0.f);
      }
    }
  }
}

// ---------------- launch ----------------

extern "C" void kernel_launch(void* const* d_in, const int* in_sizes, int n_in,
                              void* d_out, int out_size, void* d_ws, size_t ws_size,
                              hipStream_t stream) {
  const float* x  = (const float*)d_in[0];
  const float* w1 = (const float*)d_in[1];
  const float* b1 = (const float*)d_in[2];
  const float* w2 = (const float*)d_in[3];
  const float* b2 = (const float*)d_in[4];
  const float* as = (const float*)d_in[5];

  const int Mrows = 64 * 196;   // 12544
  const int D = 768, H = 3072;

  char* ws = (char*)d_ws;
  size_t off = 0;
  auto align256 = [](size_t v) { return (v + 255) & ~(size_t)255; };
  unsigned* mx = (unsigned*)(ws + off); off += 256;
  char* xq8    = (char*)(ws + off);     off += align256((size_t)Mrows * D);
  char* w1q8   = (char*)(ws + off);     off += align256((size_t)H * D);
  char* w2q8   = (char*)(ws + off);     off += align256((size_t)D * H);
  float* b1i = (float*)(ws + off); off += align256((size_t)H * 4);
  float* b2i = (float*)(ws + off); off += align256((size_t)D * 4);
  float* stab = (float*)(ws + off); off += align256((size_t)Mrows * 48 * 4);
  float* srow = (float*)(ws + off); off += align256((size_t)Mrows * 4);
  unsigned char* hq  = (unsigned char*)(ws + off); off += align256((size_t)Mrows * H);
  unsigned char* hq2 = (unsigned char*)(ws + off); off += align256((size_t)Mrows * H);
  if (off > ws_size) return;

  float* out = (float*)d_out;
  float* s_out = out + (out_size - 1);

  hipMemsetAsync(mx, 0, 8, stream);

  const int nw4 = H * D / 4;
  prep_kernel<<<dim3(96, 2), dim3(256), 0, stream>>>(
      (const float4*)w1, (const float4*)w2, nw4, mx);
  quantwb_kernel<<<dim3(1024, 4), dim3(256), 0, stream>>>(
      w1, w2, (unsigned char*)w1q8, (unsigned*)w2q8,
      (const float4*)x, (uchar4*)xq8, Mrows * D / 4,
      b1, b2, b1i, b2i, mx, as, s_out, nw4, H, D);

  // fc1: int8 128x128 single-buffer 32KB, 2352 blocks, Kb = 768
  gemm_fc1<<<dim3((Mrows / 128) * (H / 128)), dim3(256), 0, stream>>>(
      xq8, w1q8, b1i, hq, stab, Mrows, H, D);
  // requant: per-64col-chunk -> per-row scales, 4 rows/block
  requant_kernel<<<dim3(Mrows / 4), dim3(256), 0, stream>>>(
      (const uint4*)hq, (uint4*)hq2, stab, srow, Mrows);
  // fc2: int8 128x128 single-buffer 32KB, 588 blocks (all co-resident), Kb = 3072
  gemm_fc2<<<dim3((Mrows / 128) * (D / 128)), dim3(256), 0, stream>>>(
      (const char*)hq2, w2q8, b2i, srow, out, Mrows, D, H);
}

// Round 18
// 125.693 us; speedup vs baseline: 1.2411x; 1.0641x over previous
//
#include <hip/hip_runtime.h>
#include <hip/hip_bf16.h>
#include <type_traits>

typedef __attribute__((ext_vector_type(4))) float f32x4;
typedef __attribute__((ext_vector_type(4))) int   i32x4;

static __device__ __forceinline__ void stage16(const void* g, void* l) {
  __builtin_amdgcn_global_load_lds((const __attribute__((address_space(1))) void*)g,
                                   (__attribute__((address_space(3))) void*)l,
                                   16, 0, 0);
}

// ---------------- prep: maxabs(w1/w2), one slot per block (no atomics) ----------------
__global__ void prep_kernel(const float4* __restrict__ w1, const float4* __restrict__ w2,
                            int n4w, unsigned* __restrict__ mxs) {
  __shared__ unsigned red[4];
  const float4* w = blockIdx.y ? w2 : w1;
  unsigned m = 0;
  const int stride = gridDim.x * blockDim.x;
  for (int i = blockIdx.x * blockDim.x + threadIdx.x; i < n4w; i += stride) {
    float4 v = w[i];
    unsigned a;
    a = __float_as_uint(fabsf(v.x)); m = m > a ? m : a;
    a = __float_as_uint(fabsf(v.y)); m = m > a ? m : a;
    a = __float_as_uint(fabsf(v.z)); m = m > a ? m : a;
    a = __float_as_uint(fabsf(v.w)); m = m > a ? m : a;
  }
#pragma unroll
  for (int off = 32; off > 0; off >>= 1) {
    unsigned t = (unsigned)__shfl_down((int)m, off, 64);
    m = m > t ? m : t;
  }
  if ((threadIdx.x & 63) == 0) red[threadIdx.x >> 6] = m;
  __syncthreads();
  if (threadIdx.x == 0) {
    unsigned t0 = red[0] > red[1] ? red[0] : red[1];
    unsigned t1 = red[2] > red[3] ? red[2] : red[3];
    mxs[blockIdx.y * 96 + blockIdx.x] = t0 > t1 ? t0 : t1;   // deterministic slot write
  }
}

static __device__ __forceinline__ float reduce_scale(const unsigned* s) {
  unsigned m = 0;
#pragma unroll
  for (int i = 0; i < 96; ++i) { unsigned v = s[i]; m = m > v ? m : v; }
  return __uint_as_float(m) / 127.0f;
}

// y==0: w1 -> int8 (linear) ; y==1: w2 -> int8 pi-permuted within 64-k groups
// (byte p=4*dl+i holds k=dl+16*i) ; y==2: x -> int8 ; y==3 blk0: biases + scale.
__global__ void quantwb_kernel(const float* __restrict__ w1, const float* __restrict__ w2,
                               unsigned char* __restrict__ w1q, unsigned* __restrict__ w2qw,
                               const float4* __restrict__ x, uchar4* __restrict__ xq, int n4x,
                               const float* __restrict__ b1, const float* __restrict__ b2,
                               float* __restrict__ b1i, float* __restrict__ b2i,
                               const unsigned* __restrict__ mxs, const float* __restrict__ a_s,
                               float* __restrict__ s_out, int n4, int H, int D) {
  const int stride = gridDim.x * blockDim.x;
  if (blockIdx.y == 0) {
    const float ws1 = reduce_scale(mxs);
    const float4* w = (const float4*)w1;
    uchar4* wq = (uchar4*)w1q;
    for (int i = blockIdx.x * blockDim.x + threadIdx.x; i < n4; i += stride) {
      float4 v = w[i];
      uchar4 o;
      o.x = (unsigned char)(char)fminf(fmaxf(rintf(v.x / ws1), -127.f), 127.f);
      o.y = (unsigned char)(char)fminf(fmaxf(rintf(v.y / ws1), -127.f), 127.f);
      o.z = (unsigned char)(char)fminf(fmaxf(rintf(v.z / ws1), -127.f), 127.f);
      o.w = (unsigned char)(char)fminf(fmaxf(rintf(v.w / ws1), -127.f), 127.f);
      wq[i] = o;
    }
  } else if (blockIdx.y == 1) {
    const float ws2 = reduce_scale(mxs + 96);
    const int ndw = n4;                       // D*H/4 dwords
    const int dpr = H >> 2;                   // dwords per row (768)
    for (int g = blockIdx.x * blockDim.x + threadIdx.x; g < ndw; g += stride) {
      const int n = g / dpr;
      const int d = g - n * dpr;
      const int grp = d >> 4, dl = d & 15;
      const float* src = w2 + (size_t)n * H + grp * 64 + dl;
      unsigned r = 0;
#pragma unroll
      for (int i = 0; i < 4; ++i) {
        float v = src[i * 16];
        int q = (int)fminf(fmaxf(rintf(v / ws2), -127.f), 127.f);
        r |= ((unsigned)q & 0xFFu) << (i * 8);
      }
      w2qw[g] = r;
    }
  } else if (blockIdx.y == 2) {
    for (int i = blockIdx.x * blockDim.x + threadIdx.x; i < n4x; i += stride) {
      float4 v = x[i];
      uchar4 o;
      o.x = (unsigned char)(char)fminf(fmaxf(v.x, -127.f), 127.f);
      o.y = (unsigned char)(char)fminf(fmaxf(v.y, -127.f), 127.f);
      o.z = (unsigned char)(char)fminf(fmaxf(v.z, -127.f), 127.f);
      o.w = (unsigned char)(char)fminf(fmaxf(v.w, -127.f), 127.f);
      xq[i] = o;
    }
  } else {
    if (blockIdx.x != 0) return;
    const float ws1 = reduce_scale(mxs);
    const float ws2 = reduce_scale(mxs + 96);
    const float s0 = a_s[0];
    const float s1 = s0 * ws1;
    const float d1 = ws1 * s0;
    const float d2 = ws2 * s1;
    if (threadIdx.x == 0) s_out[0] = s1 * ws2;
    for (int i = threadIdx.x; i < H; i += blockDim.x) {
      float q = rintf(b1[i] / d1);
      b1i[i] = fminf(fmaxf(q, -2147483647.f), 2147483647.f);
    }
    for (int i = threadIdx.x; i < D; i += blockDim.x) {
      float q = rintf(b2[i] / d2);
      b2i[i] = fminf(fmaxf(q, -2147483647.f), 2147483647.f);
    }
  }
}

// ---------------- fc1: 128x128 int8, single-buffer 32KB, compile-time dims ----------------
// Epilogue: 64-col-chunk quant (barrier-free), fast rcp for 127/rmax.

template<int NBX, int NBY, int KB>
__global__ __launch_bounds__(256) void gemm_fc1(
    const char* __restrict__ A, const char* __restrict__ Bt,
    const float* __restrict__ b1f, unsigned char* __restrict__ hq,
    float* __restrict__ stab)
{
  constexpr int N = NBY * 128;
  __shared__ char lds[32768];          // As 16KB | Bs 16KB
  const int tid = threadIdx.x;
  const int lane = tid & 63;
  const int wave = tid >> 6;
  const int wr = wave >> 1;
  const int wc = wave & 1;

  // 16-row-tile bands, col-major within band (A-band ~1.5MB L2-resident)
  constexpr int bandSize = 16 * NBY;
  const int b = blockIdx.x / bandSize;
  const int local = blockIdx.x - b * bandSize;
  const int r0 = b * 16;
  const int rn = min(16, NBX - r0);
  const int c = local / rn;
  const int r = r0 + (local - c * rn);
  const int row0 = r * 128;
  const int col0 = c * 128;

  const int srw = tid >> 3;
  const int chunk = (tid & 7) ^ (srw & 7);
  const char* Ag = A + (size_t)(row0 + srw) * KB + chunk * 16;
  const char* Bg = Bt + (size_t)(col0 + srw) * KB + chunk * 16;
  char* const stAp = lds + wave * 1024;
  char* const stBp = lds + 16384 + wave * 1024;

  i32x4 acc[4][4];
#pragma unroll
  for (int i = 0; i < 4; ++i)
#pragma unroll
    for (int j = 0; j < 4; ++j) acc[i][j] = (i32x4)(0);

  const int fr = lane & 15;
  const int fg = lane >> 4;
  const int ocol_l = wc * 64 + fr;
  float bv[4];
#pragma unroll
  for (int nf = 0; nf < 4; ++nf) bv[nf] = b1f[col0 + ocol_l + nf * 16];

  const int xw = (fg ^ (fr & 7)) << 4;
  const int aoff = (wr * 64 + fr) * 128 + xw;
  const int boff = 16384 + (wc * 64 + fr) * 128 + xw;

  constexpr int nS = KB >> 7;          // 6
#pragma unroll 1
  for (int t = 0; t < nS; ++t) {
    const int hb = t << 7;
#pragma unroll
    for (int i = 0; i < 4; ++i)
      stage16(Ag + hb + (size_t)(i * 32) * KB, stAp + i * 4096);
#pragma unroll
    for (int i = 0; i < 4; ++i)
      stage16(Bg + hb + (size_t)(i * 32) * KB, stBp + i * 4096);
    __syncthreads();                   // vmcnt(0) drain + barrier: LDS ready
    i32x4 af[2][4], bf[2][4];
#pragma unroll
    for (int h = 0; h < 2; ++h) {
      const int hx = h << 6;
#pragma unroll
      for (int mi = 0; mi < 4; ++mi)
        af[h][mi] = *(const i32x4*)(lds + ((aoff ^ hx) + mi * 2048));
#pragma unroll
      for (int ni = 0; ni < 4; ++ni)
        bf[h][ni] = *(const i32x4*)(lds + ((boff ^ hx) + ni * 2048));
    }
    __builtin_amdgcn_s_setprio(1);
#pragma unroll
    for (int h = 0; h < 2; ++h)
#pragma unroll
      for (int mi = 0; mi < 4; ++mi)
#pragma unroll
        for (int ni = 0; ni < 4; ++ni)
          acc[mi][ni] = __builtin_amdgcn_mfma_i32_16x16x64_i8(
              af[h][mi], bf[h][ni], acc[mi][ni], 0, 0, 0);
    __builtin_amdgcn_s_setprio(0);
    __syncthreads();                   // all waves' reads done -> safe overwrite
  }

  // ---- epilogue: 64-col-chunk quant, barrier-free, pi-packed dword stores ----
  const int orow_l = wr * 64 + fg * 4;
  const int scol = c * 2 + wc;                 // chunk index within stab[row][2*NBY]
#pragma unroll
  for (int mf = 0; mf < 4; ++mf) {
#pragma unroll
    for (int rg = 0; rg < 4; ++rg) {
      float v0 = (float)acc[mf][0][rg] + bv[0];
      float v1 = (float)acc[mf][1][rg] + bv[1];
      float v2 = (float)acc[mf][2][rg] + bv[2];
      float v3 = (float)acc[mf][3][rg] + bv[3];
      float rmax = fmaxf(fmaxf(fabsf(v0), fabsf(v1)), fmaxf(fabsf(v2), fabsf(v3)));
#pragma unroll
      for (int m = 1; m <= 8; m <<= 1)
        rmax = fmaxf(rmax, __shfl_xor(rmax, m, 64));   // reduce over fr lanes
      const int lr = orow_l + mf * 16 + rg;
      const float inv = rmax > 0.f ? 127.f * __builtin_amdgcn_rcpf(rmax) : 0.f;
      if (fr == 0) stab[(size_t)(row0 + lr) * (2 * NBY) + scol] = rmax * (1.f / 127.f);
      unsigned pk = ((unsigned)(int)rintf(v0 * inv) & 0xFFu)
                  | (((unsigned)(int)rintf(v1 * inv) & 0xFFu) << 8)
                  | (((unsigned)(int)rintf(v2 * inv) & 0xFFu) << 16)
                  | (((unsigned)(int)rintf(v3 * inv) & 0xFFu) << 24);
      *(unsigned*)(hq + (size_t)(row0 + lr) * N + col0 + wc * 64 + fr * 4) = pk;
    }
  }
}

// ---------------- requant: per-64col-chunk h_q -> per-row h_q' + srow ----------------
__global__ void requant_kernel(const uint4* __restrict__ hq, uint4* __restrict__ hq2,
                               const float* __restrict__ stab, float* __restrict__ srow,
                               int Mrows) {
  const int row = blockIdx.x * 4 + (threadIdx.x >> 6);
  if (row >= Mrows) return;
  const int lane = threadIdx.x & 63;
  const float* st = stab + (size_t)row * 48;
  float sr = 0.f;
#pragma unroll
  for (int i = 0; i < 12; ++i) {
    float4 s4 = ((const float4*)st)[i];
    sr = fmaxf(sr, fmaxf(fmaxf(s4.x, s4.y), fmaxf(s4.z, s4.w)));
  }
  if (lane == 0) srow[row] = sr;
  const float rinv = sr > 0.f ? __builtin_amdgcn_rcpf(sr) : 0.f;
  const uint4* in = hq + (size_t)row * 192;
  uint4* outp = hq2 + (size_t)row * 192;
#pragma unroll
  for (int it = 0; it < 3; ++it) {
    const int j = lane + it * 64;
    const float ratio = st[j >> 2] * rinv;
    uint4 iv = in[j], ov;
    unsigned* ip = (unsigned*)&iv;
    unsigned* op = (unsigned*)&ov;
#pragma unroll
    for (int w = 0; w < 4; ++w) {
      unsigned rr = 0;
#pragma unroll
      for (int k = 0; k < 4; ++k) {
        int q = (int)(signed char)((ip[w] >> (k * 8)) & 0xFF);
        int nq = (int)rintf((float)q * ratio);
        rr |= ((unsigned)nq & 0xFF) << (k * 8);
      }
      op[w] = rr;
    }
    outp[j] = ov;
  }
}

// ---------------- fc2: 128x128 int8, single-buffer 32KB, compile-time dims ----------------
template<int NBX, int NBY, int KB>
__global__ __launch_bounds__(256) void gemm_fc2(
    const char* __restrict__ A, const char* __restrict__ Bt,
    const float* __restrict__ bias, const float* __restrict__ srow,
    float* __restrict__ Cout)
{
  constexpr int N = NBY * 128;
  __shared__ char lds[32768];          // As 16KB | Bs 16KB
  const int tid = threadIdx.x;
  const int lane = tid & 63;
  const int wave = tid >> 6;
  const int wr = wave >> 1;
  const int wc = wave & 1;

  constexpr int nwg = NBX * NBY;
  constexpr int q8 = nwg >> 3, r8 = nwg & 7;
  const int xcd = blockIdx.x & 7, bidx = blockIdx.x >> 3;
  const int wg = (xcd < r8 ? xcd * (q8 + 1) : r8 * (q8 + 1) + (xcd - r8) * q8) + bidx;
  const int r = wg / NBY;              // row-major: same-row tiles adjacent -> same XCD
  const int c = wg % NBY;
  const int row0 = r * 128;
  const int col0 = c * 128;

  const int srw = tid >> 3;
  const int chunk = (tid & 7) ^ (srw & 7);
  const char* Ag = A + (size_t)(row0 + srw) * KB + chunk * 16;
  const char* Bg = Bt + (size_t)(col0 + srw) * KB + chunk * 16;
  char* const stAp = lds + wave * 1024;
  char* const stBp = lds + 16384 + wave * 1024;

  i32x4 acc[4][4];
#pragma unroll
  for (int i = 0; i < 4; ++i)
#pragma unroll
    for (int j = 0; j < 4; ++j) acc[i][j] = (i32x4)(0);

  const int fr = lane & 15;
  const int fg = lane >> 4;
  const int xw = (fg ^ (fr & 7)) << 4;
  const int aoff = (wr * 64 + fr) * 128 + xw;
  const int boff = 16384 + (wc * 64 + fr) * 128 + xw;

  constexpr int nS = KB >> 7;          // 24
#pragma unroll 1
  for (int t = 0; t < nS; ++t) {
    const int hb = t << 7;
#pragma unroll
    for (int i = 0; i < 4; ++i)
      stage16(Ag + hb + (size_t)(i * 32) * KB, stAp + i * 4096);
#pragma unroll
    for (int i = 0; i < 4; ++i)
      stage16(Bg + hb + (size_t)(i * 32) * KB, stBp + i * 4096);
    __syncthreads();                   // vmcnt(0) drain + barrier: LDS ready
    i32x4 af[2][4], bf[2][4];
#pragma unroll
    for (int h = 0; h < 2; ++h) {
      const int hx = h << 6;
#pragma unroll
      for (int mi = 0; mi < 4; ++mi)
        af[h][mi] = *(const i32x4*)(lds + ((aoff ^ hx) + mi * 2048));
#pragma unroll
      for (int ni = 0; ni < 4; ++ni)
        bf[h][ni] = *(const i32x4*)(lds + ((boff ^ hx) + ni * 2048));
    }
    __builtin_amdgcn_s_setprio(1);
#pragma unroll
    for (int h = 0; h < 2; ++h)
#pragma unroll
      for (int mi = 0; mi < 4; ++mi)
#pragma unroll
        for (int ni = 0; ni < 4; ++ni)
          acc[mi][ni] = __builtin_amdgcn_mfma_i32_16x16x64_i8(
              af[h][mi], bf[h][ni], acc[mi][ni], 0, 0, 0);
    __builtin_amdgcn_s_setprio(0);
    __syncthreads();                   // all waves' reads done -> safe overwrite
  }

  const int orow = row0 + wr * 64 + fg * 4;
  const int ocol = col0 + wc * 64 + fr;
#pragma unroll
  for (int mi = 0; mi < 4; ++mi) {
    float sr[4];
#pragma unroll
    for (int rg = 0; rg < 4; ++rg) sr[rg] = srow[orow + mi * 16 + rg];
#pragma unroll
    for (int ni = 0; ni < 4; ++ni) {
      const int col = ocol + ni * 16;
      const float bvv = bias[col];
#pragma unroll
      for (int rg = 0; rg < 4; ++rg) {
        float v = sr[rg] * (float)acc[mi][ni][rg] + bvv;
        Cout[(size_t)(orow + mi * 16 + rg) * N + col] = fmaxf(v, 0.f);
      }
    }
  }
}

// ---------------- launch ----------------

extern "C" void kernel_launch(void* const* d_in, const int* in_sizes, int n_in,
                              void* d_out, int out_size, void* d_ws, size_t ws_size,
                              hipStream_t stream) {
  const float* x  = (const float*)d_in[0];
  const float* w1 = (const float*)d_in[1];
  const float* b1 = (const float*)d_in[2];
  const float* w2 = (const float*)d_in[3];
  const float* b2 = (const float*)d_in[4];
  const float* as = (const float*)d_in[5];

  const int Mrows = 64 * 196;   // 12544
  const int D = 768, H = 3072;

  char* ws = (char*)d_ws;
  size_t off = 0;
  auto align256 = [](size_t v) { return (v + 255) & ~(size_t)255; };
  unsigned* mxs = (unsigned*)(ws + off); off += align256(192 * 4);
  char* xq8    = (char*)(ws + off);     off += align256((size_t)Mrows * D);
  char* w1q8   = (char*)(ws + off);     off += align256((size_t)H * D);
  char* w2q8   = (char*)(ws + off);     off += align256((size_t)D * H);
  float* b1i = (float*)(ws + off); off += align256((size_t)H * 4);
  float* b2i = (float*)(ws + off); off += align256((size_t)D * 4);
  float* stab = (float*)(ws + off); off += align256((size_t)Mrows * 48 * 4);
  float* srow = (float*)(ws + off); off += align256((size_t)Mrows * 4);
  unsigned char* hq  = (unsigned char*)(ws + off); off += align256((size_t)Mrows * H);
  unsigned char* hq2 = (unsigned char*)(ws + off); off += align256((size_t)Mrows * H);
  if (off > ws_size) return;

  float* out = (float*)d_out;
  float* s_out = out + (out_size - 1);

  const int nw4 = H * D / 4;
  prep_kernel<<<dim3(96, 2), dim3(256), 0, stream>>>(
      (const float4*)w1, (const float4*)w2, nw4, mxs);
  quantwb_kernel<<<dim3(1024, 4), dim3(256), 0, stream>>>(
      w1, w2, (unsigned char*)w1q8, (unsigned*)w2q8,
      (const float4*)x, (uchar4*)xq8, Mrows * D / 4,
      b1, b2, b1i, b2i, mxs, as, s_out, nw4, H, D);

  // fc1: int8 128x128 single-buffer 32KB, 98x24 = 2352 blocks, KB=768
  gemm_fc1<98, 24, 768><<<dim3(2352), dim3(256), 0, stream>>>(
      xq8, w1q8, b1i, hq, stab);
  // requant: per-64col-chunk -> per-row scales, 4 rows/block
  requant_kernel<<<dim3(Mrows / 4), dim3(256), 0, stream>>>(
      (const uint4*)hq, (uint4*)hq2, stab, srow, Mrows);
  // fc2: int8 128x128 single-buffer 32KB, 98x6 = 588 blocks (all co-resident), KB=3072
  gemm_fc2<98, 6, 3072><<<dim3(588), dim3(256), 0, stream>>>(
      (const char*)hq2, w2q8, b2i, srow, out);
}